// Round 2
// baseline (777.952 us; speedup 1.0000x reference)
//
#include <hip/hip_runtime.h>
#include <hip/hip_bf16.h>

#define N_NODES 50000
#define N_EDGES 1600000
#define HEADS 8

typedef unsigned short u16;
typedef unsigned int u32;

__device__ __forceinline__ float bf2f(u16 u) {
  union { u32 i; float f; } v; v.i = ((u32)u) << 16; return v.f;
}
__device__ __forceinline__ u16 f2bf(float f) {
  union { float f; u32 i; } v; v.f = f;
  u32 r = v.i + 0x7fff + ((v.i >> 16) & 1);  // round-nearest-even
  return (u16)(r >> 16);
}

// ---------------- dtype auto-detection ----------------
// flags[0] = 1 if float arrays are fp32 (else bf16)
// flags[1] = 1 if edge_index is int64 (else int32)
__global__ void k_detect(const u16* __restrict__ x, const u32* __restrict__ ei,
                         int* __restrict__ flags) {
  __shared__ int cbig, cnz;
  if (threadIdx.x == 0) { cbig = 0; cnz = 0; }
  __syncthreads();
  int lb = 0, ln = 0;
  for (int i = threadIdx.x; i < 4096; i += 256) {
    int ex = (x[i] >> 7) & 0xff;          // bf16 exponent field
    lb += (ex >= 140);                    // |v| >= 2^13: impossible for real bf16 data
    if (i < 2048) ln += (ei[2 * i + 1] != 0);  // odd words: 0 iff int64 (values < 2^31)
  }
  atomicAdd(&cbig, lb); atomicAdd(&cnz, ln);
  __syncthreads();
  if (threadIdx.x == 0) {
    flags[0] = (cbig > 16) ? 1 : 0;
    flags[1] = (cnz == 0) ? 1 : 0;
  }
}

// generic float-array normalizer -> fp32
__global__ void k_convf(const void* __restrict__ in, float* __restrict__ out, int n,
                        const int* __restrict__ flags) {
  int i = blockIdx.x * 256 + threadIdx.x;
  if (i >= n) return;
  if (flags[0]) out[i] = ((const float*)in)[i];
  else          out[i] = bf2f(((const u16*)in)[i]);
}

// edge_index normalizer -> int32 src/dst; also counts in-degree (fused k_count)
__global__ void k_convi(const int* __restrict__ ei, int* __restrict__ src,
                        int* __restrict__ dst, int* __restrict__ deg,
                        const int* __restrict__ flags) {
  int e = blockIdx.x * 256 + threadIdx.x;
  if (e >= N_EDGES) return;
  int s, d;
  if (flags[1]) { s = ei[2 * e]; d = ei[2 * (N_EDGES + e)]; }  // int64 low words
  else          { s = ei[e];     d = ei[N_EDGES + e]; }
  src[e] = s; dst[e] = d;
  atomicAdd(&deg[d], 1);
}

// ---------------- CSR construction ----------------
__global__ void k_scan1(const int* __restrict__ deg, int* __restrict__ bsum, int N) {
  __shared__ int tmp[256];
  int t = threadIdx.x, i = blockIdx.x * 256 + t;
  int v = (i < N) ? deg[i] + 1 : 0;  // +1 self-loop
  tmp[t] = v; __syncthreads();
  for (int o = 128; o; o >>= 1) { if (t < o) tmp[t] += tmp[t + o]; __syncthreads(); }
  if (t == 0) bsum[blockIdx.x] = tmp[0];
}

__global__ void k_scan2(const int* __restrict__ bsum, int* __restrict__ boff, int NB) {
  __shared__ int tmp[256];
  int t = threadIdx.x;
  int v = (t < NB) ? bsum[t] : 0;
  tmp[t] = v; __syncthreads();
  for (int o = 1; o < 256; o <<= 1) {
    int x = (t >= o) ? tmp[t - o] : 0; __syncthreads();
    tmp[t] += x; __syncthreads();
  }
  if (t < NB) boff[t] = tmp[t] - v;  // exclusive
}

__global__ void k_scan3(const int* __restrict__ deg, const int* __restrict__ boff,
                        int* __restrict__ row_start, int* __restrict__ pos, int N) {
  __shared__ int tmp[256];
  int t = threadIdx.x, i = blockIdx.x * 256 + t;
  int v = (i < N) ? deg[i] + 1 : 0;
  tmp[t] = v; __syncthreads();
  for (int o = 1; o < 256; o <<= 1) {
    int x = (t >= o) ? tmp[t - o] : 0; __syncthreads();
    tmp[t] += x; __syncthreads();
  }
  if (i < N) { int rs = boff[blockIdx.x] + tmp[t] - v; row_start[i] = rs; pos[i] = rs; }
}

__global__ void k_scatter(const int* __restrict__ src, const int* __restrict__ dst,
                          int* __restrict__ pos, int* __restrict__ csr, int E) {
  int e = blockIdx.x * 256 + threadIdx.x;
  if (e < E) { int p = atomicAdd(&pos[dst[e]], 1); csr[p] = src[e]; }
}

__global__ void k_selfloop(const int* __restrict__ pos, int* __restrict__ csr, int N) {
  int n = blockIdx.x * 256 + threadIdx.x;
  if (n < N) csr[pos[n]] = n;  // pos[n] == row_start[n] + deg[n] after scatter
}

// ---------------- GEMM: fp32, 64x64 tile, optional BN+ELU on A-load ----------------
template <bool EPI>
__global__ __launch_bounds__(256) void k_gemm(const float* __restrict__ A,
                                              const float* __restrict__ B,
                                              const float* __restrict__ scale,
                                              const float* __restrict__ shift,
                                              float* __restrict__ C, int M, int ncoltot) {
  constexpr int K = 128, KP = K + 4;
  __shared__ float As[64 * KP];
  __shared__ float Bs[K * 64];
  int t = threadIdx.x;
  int row0 = blockIdx.x * 64, co = blockIdx.y * 64;
  // stage B tile [K x 64]
  for (int i = t; i < K * 16; i += 256) {
    int r = i >> 4, c4 = i & 15;
    ((float4*)Bs)[r * 16 + c4] = ((const float4*)B)[(size_t)r * (ncoltot >> 2) + (co >> 2) + c4];
  }
  // stage A tile [64 x K] (+ optional BN+ELU epilogue on the input)
  for (int i = t; i < 64 * (K / 4); i += 256) {
    int r = i >> 5, c4 = i & 31;
    float4 v = make_float4(0.f, 0.f, 0.f, 0.f);
    int row = row0 + r;
    if (row < M) {
      v = ((const float4*)A)[(size_t)row * (K / 4) + c4];
      if (EPI) {
        int c = c4 * 4;
        v.x = fmaf(v.x, scale[c], shift[c]);     v.x = v.x > 0.f ? v.x : __expf(v.x) - 1.f;
        v.y = fmaf(v.y, scale[c + 1], shift[c + 1]); v.y = v.y > 0.f ? v.y : __expf(v.y) - 1.f;
        v.z = fmaf(v.z, scale[c + 2], shift[c + 2]); v.z = v.z > 0.f ? v.z : __expf(v.z) - 1.f;
        v.w = fmaf(v.w, scale[c + 3], shift[c + 3]); v.w = v.w > 0.f ? v.w : __expf(v.w) - 1.f;
      }
    }
    *(float4*)&As[r * KP + c4 * 4] = v;
  }
  __syncthreads();
  int tx = t & 7, ty = t >> 3;
  int c0 = tx * 8, r0 = ty * 2;
  float acc[2][8];
#pragma unroll
  for (int i = 0; i < 2; i++) for (int j = 0; j < 8; j++) acc[i][j] = 0.f;
#pragma unroll 4
  for (int k = 0; k < K; k++) {
    float4 b0 = *(const float4*)&Bs[k * 64 + c0];
    float4 b1 = *(const float4*)&Bs[k * 64 + c0 + 4];
    float a0 = As[r0 * KP + k];
    float a1 = As[(r0 + 1) * KP + k];
    acc[0][0] = fmaf(a0, b0.x, acc[0][0]); acc[0][1] = fmaf(a0, b0.y, acc[0][1]);
    acc[0][2] = fmaf(a0, b0.z, acc[0][2]); acc[0][3] = fmaf(a0, b0.w, acc[0][3]);
    acc[0][4] = fmaf(a0, b1.x, acc[0][4]); acc[0][5] = fmaf(a0, b1.y, acc[0][5]);
    acc[0][6] = fmaf(a0, b1.z, acc[0][6]); acc[0][7] = fmaf(a0, b1.w, acc[0][7]);
    acc[1][0] = fmaf(a1, b0.x, acc[1][0]); acc[1][1] = fmaf(a1, b0.y, acc[1][1]);
    acc[1][2] = fmaf(a1, b0.z, acc[1][2]); acc[1][3] = fmaf(a1, b0.w, acc[1][3]);
    acc[1][4] = fmaf(a1, b1.x, acc[1][4]); acc[1][5] = fmaf(a1, b1.y, acc[1][5]);
    acc[1][6] = fmaf(a1, b1.z, acc[1][6]); acc[1][7] = fmaf(a1, b1.w, acc[1][7]);
  }
#pragma unroll
  for (int i = 0; i < 2; i++) {
    int row = row0 + r0 + i;
    if (row < M) {
      float4* cp = (float4*)&C[(size_t)row * ncoltot + co + c0];
      cp[0] = make_float4(acc[i][0], acc[i][1], acc[i][2], acc[i][3]);
      cp[1] = make_float4(acc[i][4], acc[i][5], acc[i][6], acc[i][7]);
    }
  }
}

// ---------------- per-node attention coefficients, layer 1 ----------------
__global__ void k_alpha1(const float* __restrict__ h1, const float* __restrict__ a1s,
                         const float* __restrict__ a1d, float* __restrict__ as_out,
                         float* __restrict__ ad_out, int N) {
  int idx = blockIdx.x * 256 + threadIdx.x;
  if (idx >= N * HEADS) return;
  int n = idx >> 3, h = idx & 7;
  const float4* hp = (const float4*)&h1[(size_t)n * 128 + h * 16];
  float s = 0.f, d = 0.f;
#pragma unroll
  for (int q = 0; q < 4; q++) {
    float4 v = hp[q];
    int b = h * 16 + q * 4;
    s += v.x * a1s[b] + v.y * a1s[b + 1] + v.z * a1s[b + 2] + v.w * a1s[b + 3];
    d += v.x * a1d[b] + v.y * a1d[b + 1] + v.z * a1d[b + 2] + v.w * a1d[b + 3];
  }
  as_out[idx] = s; ad_out[idx] = d;
}

// ---------------- aggregation layer 1: wave per node, online softmax ----------------
__global__ __launch_bounds__(256) void k_agg1(const float* __restrict__ h1,
                                              const float* __restrict__ as_,
                                              const float* __restrict__ ad_,
                                              const int* __restrict__ csr,
                                              const int* __restrict__ row_start,
                                              const int* __restrict__ deg,
                                              const float* __restrict__ b1,
                                              float* __restrict__ out, int N) {
  int w = threadIdx.x >> 6;
  int node = blockIdx.x * 4 + w;
  if (node >= N) return;
  int l = threadIdx.x & 63;
  int c0 = l * 2, head = l >> 3;
  int st = row_start[node], cnt = deg[node] + 1;
  float ad = ad_[node * 8 + head];
  float m = -INFINITY, s = 0.f, a0 = 0.f, a1 = 0.f;
  for (int j = 0; j < cnt; j++) {
    int srcn = csr[st + j];
    float e = as_[srcn * 8 + head] + ad;
    e = e > 0.f ? e : 0.2f * e;  // leaky relu
    float mn = fmaxf(m, e);
    float sc = __expf(m - mn);
    float p = __expf(e - mn);
    float2 hv = *(const float2*)&h1[(size_t)srcn * 128 + c0];
    s = fmaf(s, sc, p);
    a0 = fmaf(a0, sc, p * hv.x);
    a1 = fmaf(a1, sc, p * hv.y);
    m = mn;
  }
  float inv = 1.f / (s + 1e-16f);
  out[(size_t)node * 128 + c0] = fmaf(a0, inv, b1[c0]);
  out[(size_t)node * 128 + c0 + 1] = fmaf(a1, inv, b1[c0 + 1]);
}

// ---------------- batch norm stats ----------------
__global__ void k_bnstat(const float* __restrict__ h, float* __restrict__ gsum,
                         float* __restrict__ gsq, int N) {
  __shared__ float ts[256], tq[256];
  int t = threadIdx.x, col = t & 127, rr = t >> 7;
  int row0 = blockIdx.x * 128;
  float s = 0.f, q = 0.f;
  for (int r = rr; r < 128; r += 2) {
    int row = row0 + r;
    if (row < N) { float v = h[(size_t)row * 128 + col]; s += v; q = fmaf(v, v, q); }
  }
  ts[t] = s; tq[t] = q; __syncthreads();
  if (t < 128) {
    atomicAdd(&gsum[t], ts[t] + ts[t + 128]);
    atomicAdd(&gsq[t], tq[t] + tq[t + 128]);
  }
}

__global__ void k_bnfin(const float* __restrict__ gsum, const float* __restrict__ gsq,
                        const float* __restrict__ gamma, const float* __restrict__ beta,
                        float* __restrict__ scale, float* __restrict__ shift, int N) {
  int t = threadIdx.x;
  if (t >= 128) return;
  float mu = gsum[t] / (float)N;
  float var = fmaxf(gsq[t] / (float)N - mu * mu, 0.f);
  float s = gamma[t] * rsqrtf(var + 1e-5f);
  scale[t] = s;
  shift[t] = beta[t] - mu * s;
}

// ---------------- per-node attention coefficients, layer 2 ----------------
__global__ void k_alpha2(const float* __restrict__ h2, const float* __restrict__ a2s,
                         const float* __restrict__ a2d, float* __restrict__ as_out,
                         float* __restrict__ ad_out, int N) {
  int w = threadIdx.x >> 6;
  int node = blockIdx.x * 4 + w;
  if (node >= N) return;
  int l = threadIdx.x & 63;
  float v = h2[(size_t)node * 64 + l];
  float vs = v * a2s[l], vd = v * a2d[l];
  for (int o = 32; o; o >>= 1) { vs += __shfl_xor(vs, o, 64); vd += __shfl_xor(vd, o, 64); }
  if (l == 0) { as_out[node] = vs; ad_out[node] = vd; }
}

// ---------------- aggregation layer 2 -> output (dtype per flag) ----------------
__global__ __launch_bounds__(256) void k_agg2(const float* __restrict__ h2,
                                              const float* __restrict__ as_,
                                              const float* __restrict__ ad_,
                                              const int* __restrict__ csr,
                                              const int* __restrict__ row_start,
                                              const int* __restrict__ deg,
                                              const float* __restrict__ b2,
                                              void* __restrict__ out,
                                              const int* __restrict__ flags, int N) {
  int w = threadIdx.x >> 6;
  int node = blockIdx.x * 4 + w;
  if (node >= N) return;
  int l = threadIdx.x & 63;
  int st = row_start[node], cnt = deg[node] + 1;
  float ad = ad_[node];
  float m = -INFINITY, s = 0.f, a = 0.f;
  for (int j = 0; j < cnt; j++) {
    int srcn = csr[st + j];
    float e = as_[srcn] + ad;
    e = e > 0.f ? e : 0.2f * e;
    float mn = fmaxf(m, e);
    float sc = __expf(m - mn);
    float p = __expf(e - mn);
    float hv = h2[(size_t)srcn * 64 + l];
    s = fmaf(s, sc, p);
    a = fmaf(a, sc, p * hv);
    m = mn;
  }
  float r = a / (s + 1e-16f) + b2[l];
  size_t idx = (size_t)node * 64 + l;
  if (flags[0]) ((float*)out)[idx] = r;   // fp32 story
  else          ((u16*)out)[idx] = f2bf(r);  // bf16 story
}

extern "C" void kernel_launch(void* const* d_in, const int* in_sizes, int n_in,
                              void* d_out, int out_size, void* d_ws, size_t ws_size,
                              hipStream_t stream) {
  const void* x   = d_in[0];
  const int*  ei  = (const int*)d_in[1];
  const void* W1  = d_in[2];
  const void* a1s = d_in[3];
  const void* a1d = d_in[4];
  const void* b1  = d_in[5];
  const void* gam = d_in[6];
  const void* bet = d_in[7];
  const void* W2  = d_in[8];
  const void* a2s = d_in[9];
  const void* a2d = d_in[10];
  const void* b2  = d_in[11];

  char* ws = (char*)d_ws;
  size_t off = 0;
  auto alloc = [&](size_t bytes) -> void* {
    void* p = ws + off;
    off += (bytes + 255) & ~(size_t)255;
    return p;
  };
  int* flags = (int*)alloc(256);
  // deg + gsum + gsq contiguous: one memset zeroes all
  int* deg = (int*)alloc((size_t)N_NODES * 4 + 1024);
  float* gsum = (float*)((char*)deg + (size_t)N_NODES * 4);
  float* gsq = gsum + 128;
  int* row_start = (int*)alloc((size_t)N_NODES * 4);
  int* pos = (int*)alloc((size_t)N_NODES * 4);
  int* bsum = (int*)alloc(1024);
  int* boff = (int*)alloc(1024);
  int* srcA = (int*)alloc((size_t)N_EDGES * 4);
  int* dstA = (int*)alloc((size_t)N_EDGES * 4);
  int* csr = (int*)alloc((size_t)(N_EDGES + N_NODES) * 4);
  float* xf   = (float*)alloc((size_t)N_NODES * 128 * 4);
  float* W1f  = (float*)alloc(128 * 128 * 4);
  float* W2f  = (float*)alloc(128 * 64 * 4);
  float* a1sf = (float*)alloc(512);
  float* a1df = (float*)alloc(512);
  float* b1f  = (float*)alloc(512);
  float* gamf = (float*)alloc(512);
  float* betf = (float*)alloc(512);
  float* a2sf = (float*)alloc(256);
  float* a2df = (float*)alloc(256);
  float* b2f  = (float*)alloc(256);
  float* h1 = (float*)alloc((size_t)N_NODES * 128 * 4);
  float* al1s = (float*)alloc((size_t)N_NODES * 8 * 4);
  float* al1d = (float*)alloc((size_t)N_NODES * 8 * 4);
  float* h1o = (float*)alloc((size_t)N_NODES * 128 * 4);
  float* scale = (float*)alloc(512);
  float* shift = (float*)alloc(512);
  float* h2 = (float*)alloc((size_t)N_NODES * 64 * 4);
  float* al2s = (float*)alloc((size_t)N_NODES * 4);
  float* al2d = (float*)alloc((size_t)N_NODES * 4);
  if (off > ws_size) return;  // workspace too small: leave output zero (diagnosable)

  hipMemsetAsync(deg, 0, (size_t)N_NODES * 4 + 1024, stream);

  k_detect<<<1, 256, 0, stream>>>((const u16*)x, (const u32*)ei, flags);

  // normalize inputs
  k_convi<<<(N_EDGES + 255) / 256, 256, 0, stream>>>(ei, srcA, dstA, deg, flags);
  k_convf<<<(N_NODES * 128 + 255) / 256, 256, 0, stream>>>(x, xf, N_NODES * 128, flags);
  k_convf<<<64, 256, 0, stream>>>(W1, W1f, 128 * 128, flags);
  k_convf<<<32, 256, 0, stream>>>(W2, W2f, 128 * 64, flags);
  k_convf<<<1, 256, 0, stream>>>(a1s, a1sf, 128, flags);
  k_convf<<<1, 256, 0, stream>>>(a1d, a1df, 128, flags);
  k_convf<<<1, 256, 0, stream>>>(b1, b1f, 128, flags);
  k_convf<<<1, 256, 0, stream>>>(gam, gamf, 128, flags);
  k_convf<<<1, 256, 0, stream>>>(bet, betf, 128, flags);
  k_convf<<<1, 256, 0, stream>>>(a2s, a2sf, 64, flags);
  k_convf<<<1, 256, 0, stream>>>(a2d, a2df, 64, flags);
  k_convf<<<1, 256, 0, stream>>>(b2, b2f, 64, flags);

  const int NB = (N_NODES + 255) / 256;  // 196
  k_scan1<<<NB, 256, 0, stream>>>(deg, bsum, N_NODES);
  k_scan2<<<1, 256, 0, stream>>>(bsum, boff, NB);
  k_scan3<<<NB, 256, 0, stream>>>(deg, boff, row_start, pos, N_NODES);
  k_scatter<<<(N_EDGES + 255) / 256, 256, 0, stream>>>(srcA, dstA, pos, csr, N_EDGES);
  k_selfloop<<<NB, 256, 0, stream>>>(pos, csr, N_NODES);

  dim3 g1((N_NODES + 63) / 64, 2);
  k_gemm<false><<<g1, 256, 0, stream>>>(xf, W1f, nullptr, nullptr, h1, N_NODES, 128);
  k_alpha1<<<(N_NODES * HEADS + 255) / 256, 256, 0, stream>>>(h1, a1sf, a1df, al1s, al1d, N_NODES);
  k_agg1<<<(N_NODES + 3) / 4, 256, 0, stream>>>(h1, al1s, al1d, csr, row_start, deg, b1f, h1o, N_NODES);

  k_bnstat<<<(N_NODES + 127) / 128, 256, 0, stream>>>(h1o, gsum, gsq, N_NODES);
  k_bnfin<<<1, 128, 0, stream>>>(gsum, gsq, gamf, betf, scale, shift, N_NODES);

  dim3 g2((N_NODES + 63) / 64, 1);
  k_gemm<true><<<g2, 256, 0, stream>>>(h1o, W2f, scale, shift, h2, N_NODES, 64);
  k_alpha2<<<(N_NODES + 3) / 4, 256, 0, stream>>>(h2, a2sf, a2df, al2s, al2d, N_NODES);
  k_agg2<<<(N_NODES + 3) / 4, 256, 0, stream>>>(h2, al2s, al2d, csr, row_start, deg, b2f,
                                                d_out, flags, N_NODES);
}

// Round 3
// 551.681 us; speedup vs baseline: 1.4101x; 1.4101x over previous
//
#include <hip/hip_runtime.h>
#include <hip/hip_bf16.h>

#define N_NODES 50000
#define N_EDGES 1600000
#define HEADS 8

typedef unsigned short u16;
typedef unsigned int u32;

__device__ __forceinline__ float bf2f(u16 u) {
  union { u32 i; float f; } v; v.i = ((u32)u) << 16; return v.f;
}
__device__ __forceinline__ float bflo(u32 p) {  // low bf16 of packed pair
  union { u32 i; float f; } v; v.i = p << 16; return v.f;
}
__device__ __forceinline__ float bfhi(u32 p) {  // high bf16 of packed pair
  union { u32 i; float f; } v; v.i = p & 0xffff0000u; return v.f;
}
__device__ __forceinline__ u16 f2bf(float f) {
  union { float f; u32 i; } v; v.f = f;
  u32 r = v.i + 0x7fff + ((v.i >> 16) & 1);  // RNE
  return (u16)(r >> 16);
}
__device__ __forceinline__ u32 pack2(float a, float b) {
  return (u32)f2bf(a) | ((u32)f2bf(b) << 16);
}

// ---------------- dtype auto-detection (proven in round 2) ----------------
__global__ void k_detect(const u16* __restrict__ x, const u32* __restrict__ ei,
                         int* __restrict__ flags) {
  __shared__ int cbig, cnz;
  if (threadIdx.x == 0) { cbig = 0; cnz = 0; }
  __syncthreads();
  int lb = 0, ln = 0;
  for (int i = threadIdx.x; i < 4096; i += 256) {
    int ex = (x[i] >> 7) & 0xff;
    lb += (ex >= 140);
    if (i < 2048) ln += (ei[2 * i + 1] != 0);
  }
  atomicAdd(&cbig, lb); atomicAdd(&cnz, ln);
  __syncthreads();
  if (threadIdx.x == 0) {
    flags[0] = (cbig > 16) ? 1 : 0;   // 1: floats are fp32
    flags[1] = (cnz == 0) ? 1 : 0;    // 1: edge_index is int64
  }
}

// ---------------- fused converter: all weights/vectors -> fp32 ----------------
// layout in outbuf: a1s[0,128) a1d[128) b1[256) gam[384) bet[512) a2s[640) a2d[704)
//                   b2[768) | W1[832, 832+16384) | W2[17216, 25408)
__global__ void k_convsmall(const void* a1s, const void* a1d, const void* b1,
                            const void* gam, const void* bet, const void* a2s,
                            const void* a2d, const void* b2, const void* W1,
                            const void* W2, float* __restrict__ outbuf,
                            const int* __restrict__ flags) {
  int i = blockIdx.x * 256 + threadIdx.x;
  if (i >= 25408) return;
  const void* src; int off;
  if (i >= 17216)      { src = W2;  off = i - 17216; }
  else if (i >= 832)   { src = W1;  off = i - 832; }
  else if (i >= 768)   { src = b2;  off = i - 768; }
  else if (i >= 704)   { src = a2d; off = i - 704; }
  else if (i >= 640)   { src = a2s; off = i - 640; }
  else if (i >= 512)   { src = bet; off = i - 512; }
  else if (i >= 384)   { src = gam; off = i - 384; }
  else if (i >= 256)   { src = b1;  off = i - 256; }
  else if (i >= 128)   { src = a1d; off = i - 128; }
  else                 { src = a1s; off = i; }
  outbuf[i] = flags[0] ? ((const float*)src)[off] : bf2f(((const u16*)src)[off]);
}

// edge_index -> int32 src/dst + in-degree count
__global__ void k_convi(const int* __restrict__ ei, int* __restrict__ src,
                        int* __restrict__ dst, int* __restrict__ deg,
                        const int* __restrict__ flags) {
  int e = blockIdx.x * 256 + threadIdx.x;
  if (e >= N_EDGES) return;
  int s, d;
  if (flags[1]) { s = ei[2 * e]; d = ei[2 * (N_EDGES + e)]; }
  else          { s = ei[e];     d = ei[N_EDGES + e]; }
  src[e] = s; dst[e] = d;
  atomicAdd(&deg[d], 1);
}

// ---------------- CSR construction ----------------
__global__ void k_scan1(const int* __restrict__ deg, int* __restrict__ bsum, int N) {
  __shared__ int tmp[256];
  int t = threadIdx.x, i = blockIdx.x * 256 + t;
  int v = (i < N) ? deg[i] + 1 : 0;
  tmp[t] = v; __syncthreads();
  for (int o = 128; o; o >>= 1) { if (t < o) tmp[t] += tmp[t + o]; __syncthreads(); }
  if (t == 0) bsum[blockIdx.x] = tmp[0];
}

__global__ void k_scan2(const int* __restrict__ bsum, int* __restrict__ boff, int NB) {
  __shared__ int tmp[256];
  int t = threadIdx.x;
  int v = (t < NB) ? bsum[t] : 0;
  tmp[t] = v; __syncthreads();
  for (int o = 1; o < 256; o <<= 1) {
    int x = (t >= o) ? tmp[t - o] : 0; __syncthreads();
    tmp[t] += x; __syncthreads();
  }
  if (t < NB) boff[t] = tmp[t] - v;
}

__global__ void k_scan3(const int* __restrict__ deg, const int* __restrict__ boff,
                        int* __restrict__ row_start, int* __restrict__ pos, int N) {
  __shared__ int tmp[256];
  int t = threadIdx.x, i = blockIdx.x * 256 + t;
  int v = (i < N) ? deg[i] + 1 : 0;
  tmp[t] = v; __syncthreads();
  for (int o = 1; o < 256; o <<= 1) {
    int x = (t >= o) ? tmp[t - o] : 0; __syncthreads();
    tmp[t] += x; __syncthreads();
  }
  if (i < N) { int rs = boff[blockIdx.x] + tmp[t] - v; row_start[i] = rs; pos[i] = rs; }
}

__global__ void k_scatter(const int* __restrict__ src, const int* __restrict__ dst,
                          int* __restrict__ pos, int* __restrict__ csr, int E) {
  int e = blockIdx.x * 256 + threadIdx.x;
  if (e < E) { int p = atomicAdd(&pos[dst[e]], 1); csr[p] = src[e]; }
}

__global__ void k_selfloop(const int* __restrict__ pos, int* __restrict__ csr, int N) {
  int n = blockIdx.x * 256 + threadIdx.x;
  if (n < N) csr[pos[n]] = n;
}

// ---------------- GEMM: A[M,128] x B[128,ncol] -> bf16 C ----------------
// AFLAG: A dtype from flags[0] (else bf16). EPI: BN+ELU on A-load.
template <bool EPI, bool AFLAG>
__global__ __launch_bounds__(256) void k_gemm(const void* __restrict__ A,
                                              const float* __restrict__ B,
                                              const float* __restrict__ scale,
                                              const float* __restrict__ shift,
                                              u16* __restrict__ C, int M, int ncoltot,
                                              const int* __restrict__ flags) {
  constexpr int K = 128, KP = K + 4;
  __shared__ float As[64 * KP];
  __shared__ float Bs[K * 64];
  int t = threadIdx.x;
  int row0 = blockIdx.x * 64, co = blockIdx.y * 64;
  bool af32 = AFLAG ? (flags[0] != 0) : false;
  for (int i = t; i < K * 16; i += 256) {
    int r = i >> 4, c4 = i & 15;
    ((float4*)Bs)[r * 16 + c4] = ((const float4*)B)[(size_t)r * (ncoltot >> 2) + (co >> 2) + c4];
  }
  for (int i = t; i < 64 * 32; i += 256) {
    int r = i >> 5, c4 = i & 31;
    float4 v = make_float4(0.f, 0.f, 0.f, 0.f);
    int row = row0 + r;
    if (row < M) {
      if (af32) {
        v = ((const float4*)A)[(size_t)row * 32 + c4];
      } else {
        uint2 p = ((const uint2*)A)[(size_t)row * 32 + c4];
        v.x = bflo(p.x); v.y = bfhi(p.x); v.z = bflo(p.y); v.w = bfhi(p.y);
      }
      if (EPI) {
        int c = c4 * 4;
        v.x = fmaf(v.x, scale[c],     shift[c]);     v.x = v.x > 0.f ? v.x : __expf(v.x) - 1.f;
        v.y = fmaf(v.y, scale[c + 1], shift[c + 1]); v.y = v.y > 0.f ? v.y : __expf(v.y) - 1.f;
        v.z = fmaf(v.z, scale[c + 2], shift[c + 2]); v.z = v.z > 0.f ? v.z : __expf(v.z) - 1.f;
        v.w = fmaf(v.w, scale[c + 3], shift[c + 3]); v.w = v.w > 0.f ? v.w : __expf(v.w) - 1.f;
      }
    }
    *(float4*)&As[r * KP + c4 * 4] = v;
  }
  __syncthreads();
  int tx = t & 7, ty = t >> 3;
  int c0 = tx * 8, r0 = ty * 2;
  float acc[2][8];
#pragma unroll
  for (int i = 0; i < 2; i++) for (int j = 0; j < 8; j++) acc[i][j] = 0.f;
#pragma unroll 4
  for (int k = 0; k < K; k++) {
    float4 b0 = *(const float4*)&Bs[k * 64 + c0];
    float4 b1 = *(const float4*)&Bs[k * 64 + c0 + 4];
    float a0 = As[r0 * KP + k];
    float a1 = As[(r0 + 1) * KP + k];
    acc[0][0] = fmaf(a0, b0.x, acc[0][0]); acc[0][1] = fmaf(a0, b0.y, acc[0][1]);
    acc[0][2] = fmaf(a0, b0.z, acc[0][2]); acc[0][3] = fmaf(a0, b0.w, acc[0][3]);
    acc[0][4] = fmaf(a0, b1.x, acc[0][4]); acc[0][5] = fmaf(a0, b1.y, acc[0][5]);
    acc[0][6] = fmaf(a0, b1.z, acc[0][6]); acc[0][7] = fmaf(a0, b1.w, acc[0][7]);
    acc[1][0] = fmaf(a1, b0.x, acc[1][0]); acc[1][1] = fmaf(a1, b0.y, acc[1][1]);
    acc[1][2] = fmaf(a1, b0.z, acc[1][2]); acc[1][3] = fmaf(a1, b0.w, acc[1][3]);
    acc[1][4] = fmaf(a1, b1.x, acc[1][4]); acc[1][5] = fmaf(a1, b1.y, acc[1][5]);
    acc[1][6] = fmaf(a1, b1.z, acc[1][6]); acc[1][7] = fmaf(a1, b1.w, acc[1][7]);
  }
#pragma unroll
  for (int i = 0; i < 2; i++) {
    int row = row0 + r0 + i;
    if (row < M) {
      u32* cp = (u32*)&C[(size_t)row * ncoltot + co + c0];
      cp[0] = pack2(acc[i][0], acc[i][1]);
      cp[1] = pack2(acc[i][2], acc[i][3]);
      cp[2] = pack2(acc[i][4], acc[i][5]);
      cp[3] = pack2(acc[i][6], acc[i][7]);
    }
  }
}

// ---------------- per-node attention coefficients, layer 1 (bf16 h) ----------------
__global__ void k_alpha1(const u16* __restrict__ h1b, const float* __restrict__ a1s,
                         const float* __restrict__ a1d, float* __restrict__ as_out,
                         float* __restrict__ ad_out, int N) {
  int idx = blockIdx.x * 256 + threadIdx.x;
  if (idx >= N * HEADS) return;
  int n = idx >> 3, h = idx & 7;
  const u32* hp = (const u32*)&h1b[((size_t)n << 7) + (h << 4)];
  float s = 0.f, d = 0.f;
#pragma unroll
  for (int q = 0; q < 8; q++) {
    u32 p = hp[q];
    float v0 = bflo(p), v1 = bfhi(p);
    int b = (h << 4) + q * 2;
    s = fmaf(v0, a1s[b], s); s = fmaf(v1, a1s[b + 1], s);
    d = fmaf(v0, a1d[b], d); d = fmaf(v1, a1d[b + 1], d);
  }
  as_out[idx] = s; ad_out[idx] = d;
}

// ---------------- aggregation layer 1: wave/node, exp-no-max, 4x unroll ----------------
__global__ __launch_bounds__(256) void k_agg1(const u16* __restrict__ h1b,
                                              const float* __restrict__ as_,
                                              const float* __restrict__ ad_,
                                              const int* __restrict__ csr,
                                              const int* __restrict__ row_start,
                                              const int* __restrict__ deg,
                                              const float* __restrict__ b1,
                                              u16* __restrict__ out, int N) {
  int w = threadIdx.x >> 6;
  int node = blockIdx.x * 4 + w;
  if (node >= N) return;
  int l = threadIdx.x & 63;
  int head = l >> 3;
  int st = row_start[node], cnt = deg[node] + 1;
  float ad = ad_[(node << 3) | head];
  float s = 0.f, a0 = 0.f, a1 = 0.f;
  const u32* h32 = (const u32*)h1b;
  int j = 0;
  for (; j + 4 <= cnt; j += 4) {
    int s0 = csr[st + j], s1 = csr[st + j + 1], s2 = csr[st + j + 2], s3 = csr[st + j + 3];
    float e0 = as_[(s0 << 3) | head], e1 = as_[(s1 << 3) | head];
    float e2 = as_[(s2 << 3) | head], e3 = as_[(s3 << 3) | head];
    u32 h0 = h32[(s0 << 6) | l], h1v = h32[(s1 << 6) | l];
    u32 h2v = h32[(s2 << 6) | l], h3 = h32[(s3 << 6) | l];
    e0 += ad; e0 = fmaxf(e0, 0.2f * e0); float p0 = __expf(e0);
    e1 += ad; e1 = fmaxf(e1, 0.2f * e1); float p1 = __expf(e1);
    e2 += ad; e2 = fmaxf(e2, 0.2f * e2); float p2 = __expf(e2);
    e3 += ad; e3 = fmaxf(e3, 0.2f * e3); float p3 = __expf(e3);
    s += (p0 + p1) + (p2 + p3);
    a0 = fmaf(p0, bflo(h0), a0);  a1 = fmaf(p0, bfhi(h0), a1);
    a0 = fmaf(p1, bflo(h1v), a0); a1 = fmaf(p1, bfhi(h1v), a1);
    a0 = fmaf(p2, bflo(h2v), a0); a1 = fmaf(p2, bfhi(h2v), a1);
    a0 = fmaf(p3, bflo(h3), a0);  a1 = fmaf(p3, bfhi(h3), a1);
  }
  for (; j < cnt; j++) {
    int s0 = csr[st + j];
    float e0 = as_[(s0 << 3) | head] + ad;
    e0 = fmaxf(e0, 0.2f * e0);
    float p0 = __expf(e0);
    u32 h0 = h32[(s0 << 6) | l];
    s += p0;
    a0 = fmaf(p0, bflo(h0), a0); a1 = fmaf(p0, bfhi(h0), a1);
  }
  float inv = 1.f / (s + 1e-16f);
  int c0 = l * 2;
  ((u32*)out)[((size_t)node << 6) + l] =
      pack2(fmaf(a0, inv, b1[c0]), fmaf(a1, inv, b1[c0 + 1]));
}

// ---------------- batch norm stats (bf16 input) ----------------
__global__ void k_bnstat(const u16* __restrict__ h, float* __restrict__ gsum,
                         float* __restrict__ gsq, int N) {
  __shared__ float ts[256], tq[256];
  int t = threadIdx.x, col = t & 127, rr = t >> 7;
  int row0 = blockIdx.x * 128;
  float s = 0.f, q = 0.f;
  for (int r = rr; r < 128; r += 2) {
    int row = row0 + r;
    if (row < N) {
      float v = bf2f(h[((size_t)row << 7) + col]);
      s += v; q = fmaf(v, v, q);
    }
  }
  ts[t] = s; tq[t] = q; __syncthreads();
  if (t < 128) {
    atomicAdd(&gsum[t], ts[t] + ts[t + 128]);
    atomicAdd(&gsq[t], tq[t] + tq[t + 128]);
  }
}

__global__ void k_bnfin(const float* __restrict__ gsum, const float* __restrict__ gsq,
                        const float* __restrict__ gamma, const float* __restrict__ beta,
                        float* __restrict__ scale, float* __restrict__ shift, int N) {
  int t = threadIdx.x;
  if (t >= 128) return;
  float mu = gsum[t] / (float)N;
  float var = fmaxf(gsq[t] / (float)N - mu * mu, 0.f);
  float s = gamma[t] * rsqrtf(var + 1e-5f);
  scale[t] = s;
  shift[t] = beta[t] - mu * s;
}

// ---------------- per-node attention coefficients, layer 2 ----------------
__global__ void k_alpha2(const u16* __restrict__ h2b, const float* __restrict__ a2s,
                         const float* __restrict__ a2d, float* __restrict__ as_out,
                         float* __restrict__ ad_out, int N) {
  int w = threadIdx.x >> 6;
  int node = blockIdx.x * 4 + w;
  if (node >= N) return;
  int l = threadIdx.x & 63;
  float v = bf2f(h2b[((size_t)node << 6) + l]);
  float vs = v * a2s[l], vd = v * a2d[l];
  for (int o = 32; o; o >>= 1) { vs += __shfl_xor(vs, o, 64); vd += __shfl_xor(vd, o, 64); }
  if (l == 0) { as_out[node] = vs; ad_out[node] = vd; }
}

// ---------------- aggregation layer 2 -> output ----------------
__global__ __launch_bounds__(256) void k_agg2(const u16* __restrict__ h2b,
                                              const float* __restrict__ as_,
                                              const float* __restrict__ ad_,
                                              const int* __restrict__ csr,
                                              const int* __restrict__ row_start,
                                              const int* __restrict__ deg,
                                              const float* __restrict__ b2,
                                              void* __restrict__ out,
                                              const int* __restrict__ flags, int N) {
  int w = threadIdx.x >> 6;
  int node = blockIdx.x * 4 + w;
  if (node >= N) return;
  int l = threadIdx.x & 63;
  int st = row_start[node], cnt = deg[node] + 1;
  float ad = ad_[node];
  float s = 0.f, a = 0.f;
  int j = 0;
  for (; j + 4 <= cnt; j += 4) {
    int s0 = csr[st + j], s1 = csr[st + j + 1], s2 = csr[st + j + 2], s3 = csr[st + j + 3];
    float e0 = as_[s0], e1 = as_[s1], e2 = as_[s2], e3 = as_[s3];
    u16 v0 = h2b[(s0 << 6) | l], v1 = h2b[(s1 << 6) | l];
    u16 v2 = h2b[(s2 << 6) | l], v3 = h2b[(s3 << 6) | l];
    e0 += ad; e0 = fmaxf(e0, 0.2f * e0); float p0 = __expf(e0);
    e1 += ad; e1 = fmaxf(e1, 0.2f * e1); float p1 = __expf(e1);
    e2 += ad; e2 = fmaxf(e2, 0.2f * e2); float p2 = __expf(e2);
    e3 += ad; e3 = fmaxf(e3, 0.2f * e3); float p3 = __expf(e3);
    s += (p0 + p1) + (p2 + p3);
    a = fmaf(p0, bf2f(v0), a); a = fmaf(p1, bf2f(v1), a);
    a = fmaf(p2, bf2f(v2), a); a = fmaf(p3, bf2f(v3), a);
  }
  for (; j < cnt; j++) {
    int s0 = csr[st + j];
    float e0 = as_[s0] + ad;
    e0 = fmaxf(e0, 0.2f * e0);
    float p0 = __expf(e0);
    s += p0;
    a = fmaf(p0, bf2f(h2b[(s0 << 6) | l]), a);
  }
  float r = a / (s + 1e-16f) + b2[l];
  size_t idx = ((size_t)node << 6) + l;
  if (flags[0]) ((float*)out)[idx] = r;
  else          ((u16*)out)[idx] = f2bf(r);
}

extern "C" void kernel_launch(void* const* d_in, const int* in_sizes, int n_in,
                              void* d_out, int out_size, void* d_ws, size_t ws_size,
                              hipStream_t stream) {
  const void* x   = d_in[0];
  const int*  ei  = (const int*)d_in[1];
  const void* W1  = d_in[2];
  const void* a1s = d_in[3];
  const void* a1d = d_in[4];
  const void* b1  = d_in[5];
  const void* gam = d_in[6];
  const void* bet = d_in[7];
  const void* W2  = d_in[8];
  const void* a2s = d_in[9];
  const void* a2d = d_in[10];
  const void* b2  = d_in[11];

  char* ws = (char*)d_ws;
  size_t off = 0;
  auto alloc = [&](size_t bytes) -> void* {
    void* p = ws + off;
    off += (bytes + 255) & ~(size_t)255;
    return p;
  };
  int* flags = (int*)alloc(256);
  int* deg = (int*)alloc((size_t)N_NODES * 4 + 1024);  // + gsum/gsq tail
  float* gsum = (float*)((char*)deg + (size_t)N_NODES * 4);
  float* gsq = gsum + 128;
  int* row_start = (int*)alloc((size_t)N_NODES * 4);
  int* pos = (int*)alloc((size_t)N_NODES * 4);
  int* bsum = (int*)alloc(1024);
  int* boff = (int*)alloc(1024);
  int* srcA = (int*)alloc((size_t)N_EDGES * 4);
  int* dstA = (int*)alloc((size_t)N_EDGES * 4);
  int* csr = (int*)alloc((size_t)(N_EDGES + N_NODES) * 4);
  float* smallf = (float*)alloc(25408 * 4);
  float* a1sf = smallf;        float* a1df = smallf + 128;
  float* b1f  = smallf + 256;  float* gamf = smallf + 384;
  float* betf = smallf + 512;  float* a2sf = smallf + 640;
  float* a2df = smallf + 704;  float* b2f  = smallf + 768;
  float* W1f  = smallf + 832;  float* W2f  = smallf + 17216;
  u16* h1b  = (u16*)alloc((size_t)N_NODES * 128 * 2);
  u16* h1ob = (u16*)alloc((size_t)N_NODES * 128 * 2);
  u16* h2b  = (u16*)alloc((size_t)N_NODES * 64 * 2);
  float* al1s = (float*)alloc((size_t)N_NODES * 8 * 4);
  float* al1d = (float*)alloc((size_t)N_NODES * 8 * 4);
  float* scale = (float*)alloc(512);
  float* shift = (float*)alloc(512);
  float* al2s = (float*)alloc((size_t)N_NODES * 4);
  float* al2d = (float*)alloc((size_t)N_NODES * 4);
  if (off > ws_size) return;

  hipMemsetAsync(deg, 0, (size_t)N_NODES * 4 + 1024, stream);
  k_detect<<<1, 256, 0, stream>>>((const u16*)x, (const u32*)ei, flags);

  k_convsmall<<<100, 256, 0, stream>>>(a1s, a1d, b1, gam, bet, a2s, a2d, b2, W1, W2,
                                       smallf, flags);
  k_convi<<<(N_EDGES + 255) / 256, 256, 0, stream>>>(ei, srcA, dstA, deg, flags);

  const int NB = (N_NODES + 255) / 256;
  k_scan1<<<NB, 256, 0, stream>>>(deg, bsum, N_NODES);
  k_scan2<<<1, 256, 0, stream>>>(bsum, boff, NB);
  k_scan3<<<NB, 256, 0, stream>>>(deg, boff, row_start, pos, N_NODES);
  k_scatter<<<(N_EDGES + 255) / 256, 256, 0, stream>>>(srcA, dstA, pos, csr, N_EDGES);
  k_selfloop<<<NB, 256, 0, stream>>>(pos, csr, N_NODES);

  dim3 g1((N_NODES + 63) / 64, 2);
  k_gemm<false, true><<<g1, 256, 0, stream>>>(x, W1f, nullptr, nullptr, h1b,
                                              N_NODES, 128, flags);
  k_alpha1<<<(N_NODES * HEADS + 255) / 256, 256, 0, stream>>>(h1b, a1sf, a1df,
                                                              al1s, al1d, N_NODES);
  k_agg1<<<(N_NODES + 3) / 4, 256, 0, stream>>>(h1b, al1s, al1d, csr, row_start, deg,
                                                b1f, h1ob, N_NODES);

  k_bnstat<<<(N_NODES + 127) / 128, 256, 0, stream>>>(h1ob, gsum, gsq, N_NODES);
  k_bnfin<<<1, 128, 0, stream>>>(gsum, gsq, gamf, betf, scale, shift, N_NODES);

  dim3 g2((N_NODES + 63) / 64, 1);
  k_gemm<true, false><<<g2, 256, 0, stream>>>(h1ob, W2f, scale, shift, h2b,
                                              N_NODES, 64, flags);
  k_alpha2<<<(N_NODES + 3) / 4, 256, 0, stream>>>(h2b, a2sf, a2df, al2s, al2d, N_NODES);
  k_agg2<<<(N_NODES + 3) / 4, 256, 0, stream>>>(h2b, al2s, al2d, csr, row_start, deg,
                                                b2f, d_out, flags, N_NODES);
}

// Round 4
// 400.862 us; speedup vs baseline: 1.9407x; 1.3762x over previous
//
#include <hip/hip_runtime.h>
#include <hip/hip_bf16.h>

#define N_NODES 50000
#define N_EDGES 1600000
#define HEADS 8
#define NBK 196   // buckets: dst>>8, 50000/256 -> 196
#define NBLK 196  // edge tiles: 196*8192 >= 1.6M

typedef unsigned short u16;
typedef unsigned int u32;

__device__ __forceinline__ float bf2f(u16 u) {
  union { u32 i; float f; } v; v.i = ((u32)u) << 16; return v.f;
}
__device__ __forceinline__ float bflo(u32 p) {
  union { u32 i; float f; } v; v.i = p << 16; return v.f;
}
__device__ __forceinline__ float bfhi(u32 p) {
  union { u32 i; float f; } v; v.i = p & 0xffff0000u; return v.f;
}
__device__ __forceinline__ u16 f2bf(float f) {
  union { float f; u32 i; } v; v.f = f;
  u32 r = v.i + 0x7fff + ((v.i >> 16) & 1);  // RNE
  return (u16)(r >> 16);
}
__device__ __forceinline__ u32 pack2(float a, float b) {
  return (u32)f2bf(a) | ((u32)f2bf(b) << 16);
}

// ---------------- dtype auto-detection ----------------
__global__ void k_detect(const u16* __restrict__ x, const u32* __restrict__ ei,
                         int* __restrict__ flags) {
  __shared__ int cbig, cnz;
  if (threadIdx.x == 0) { cbig = 0; cnz = 0; }
  __syncthreads();
  int lb = 0, ln = 0;
  for (int i = threadIdx.x; i < 4096; i += 256) {
    int ex = (x[i] >> 7) & 0xff;
    lb += (ex >= 140);
    if (i < 2048) ln += (ei[2 * i + 1] != 0);
  }
  atomicAdd(&cbig, lb); atomicAdd(&cnz, ln);
  __syncthreads();
  if (threadIdx.x == 0) {
    flags[0] = (cbig > 16) ? 1 : 0;   // 1: floats are fp32
    flags[1] = (cnz == 0) ? 1 : 0;    // 1: edge_index is int64
  }
}

// ---------------- fused converter: all weights/vectors -> fp32 ----------------
__global__ void k_convsmall(const void* a1s, const void* a1d, const void* b1,
                            const void* gam, const void* bet, const void* a2s,
                            const void* a2d, const void* b2, const void* W1,
                            const void* W2, float* __restrict__ outbuf,
                            const int* __restrict__ flags) {
  int i = blockIdx.x * 256 + threadIdx.x;
  if (i >= 25408) return;
  const void* src; int off;
  if (i >= 17216)      { src = W2;  off = i - 17216; }
  else if (i >= 832)   { src = W1;  off = i - 832; }
  else if (i >= 768)   { src = b2;  off = i - 768; }
  else if (i >= 704)   { src = a2d; off = i - 704; }
  else if (i >= 640)   { src = a2s; off = i - 640; }
  else if (i >= 512)   { src = bet; off = i - 512; }
  else if (i >= 384)   { src = gam; off = i - 384; }
  else if (i >= 256)   { src = b1;  off = i - 256; }
  else if (i >= 128)   { src = a1d; off = i - 128; }
  else                 { src = a1s; off = i; }
  outbuf[i] = flags[0] ? ((const float*)src)[off] : bf2f(((const u16*)src)[off]);
}

// ---------------- CSR build, atomic-free (two-level LDS counting sort) -------
// Phase 1: per-(bucket,block) histogram. bucket = dst>>8.
__global__ __launch_bounds__(256) void k_hist(const int* __restrict__ ei,
                                              int* __restrict__ H,
                                              int* __restrict__ totals,
                                              const int* __restrict__ flags) {
  __shared__ int hist[NBK];
  int t = threadIdx.x, blk = blockIdx.x;
  for (int i = t; i < NBK; i += 256) hist[i] = 0;
  __syncthreads();
  bool i64 = flags[1] != 0;
  int base = blk * 8192;
  for (int k = 0; k < 32; k++) {
    int e = base + k * 256 + t;
    if (e < N_EDGES) {
      int d = i64 ? ei[2 * (N_EDGES + e)] : ei[N_EDGES + e];
      atomicAdd(&hist[d >> 8], 1);
    }
  }
  __syncthreads();
  for (int i = t; i < NBK; i += 256) {
    H[i * NBLK + blk] = hist[i];
    atomicAdd(&totals[i], hist[i]);
  }
}

// Phase 2a: exclusive scan of bucket totals -> bucketBase[NBK+1]
__global__ void k_scan_tot(const int* __restrict__ totals, int* __restrict__ bucketBase) {
  __shared__ int tmp[256];
  int t = threadIdx.x;
  int v = (t < NBK) ? totals[t] : 0;
  tmp[t] = v; __syncthreads();
  for (int o = 1; o < 256; o <<= 1) {
    int x = (t >= o) ? tmp[t - o] : 0; __syncthreads();
    tmp[t] += x; __syncthreads();
  }
  if (t < NBK) bucketBase[t] = tmp[t] - v;
  if (t == NBK - 1) bucketBase[NBK] = tmp[t];
}

// Phase 2b: per-bucket scan over blocks -> P[bucket][block] start offset
__global__ void k_scan_blk(const int* __restrict__ H, const int* __restrict__ bucketBase,
                           int* __restrict__ P) {
  __shared__ int tmp[256];
  int t = threadIdx.x, b = blockIdx.x;
  int v = (t < NBLK) ? H[b * NBLK + t] : 0;
  tmp[t] = v; __syncthreads();
  for (int o = 1; o < 256; o <<= 1) {
    int x = (t >= o) ? tmp[t - o] : 0; __syncthreads();
    tmp[t] += x; __syncthreads();
  }
  if (t < NBLK) P[b * NBLK + t] = bucketBase[b] + tmp[t] - v;
}

// Phase 3: scatter edges into bucket regions (LDS cursors, no global atomics)
__global__ __launch_bounds__(256) void k_bucket(const int* __restrict__ ei,
                                                const int* __restrict__ P,
                                                u32* __restrict__ buf,
                                                const int* __restrict__ flags) {
  __shared__ int cur[NBK];
  int t = threadIdx.x, blk = blockIdx.x;
  for (int i = t; i < NBK; i += 256) cur[i] = P[i * NBLK + blk];
  __syncthreads();
  bool i64 = flags[1] != 0;
  int base = blk * 8192;
  for (int k = 0; k < 32; k++) {
    int e = base + k * 256 + t;
    if (e < N_EDGES) {
      int s = i64 ? ei[2 * e] : ei[e];
      int d = i64 ? ei[2 * (N_EDGES + e)] : ei[N_EDGES + e];
      int pos = atomicAdd(&cur[d >> 8], 1);
      buf[pos] = ((u32)(d & 255) << 16) | (u32)s;  // src < 50000 fits 16 bits
    }
  }
}

// Phase 4: per-bucket local CSR (LDS count + scan + scatter within 32KB window)
__global__ __launch_bounds__(256) void k_csr(const u32* __restrict__ buf,
                                             const int* __restrict__ bucketBase,
                                             int* __restrict__ row_start,
                                             int* __restrict__ deg,
                                             int* __restrict__ csr, int N) {
  __shared__ int cnt[256], scn[256], cur[256];
  int b = blockIdx.x, t = threadIdx.x;
  int lo = bucketBase[b], hi = bucketBase[b + 1];
  cnt[t] = 0; __syncthreads();
  for (int e = lo + t; e < hi; e += 256) atomicAdd(&cnt[(buf[e] >> 16) & 255], 1);
  __syncthreads();
  int v = cnt[t];
  scn[t] = v; __syncthreads();
  for (int o = 1; o < 256; o <<= 1) {
    int x = (t >= o) ? scn[t - o] : 0; __syncthreads();
    scn[t] += x; __syncthreads();
  }
  int excl = scn[t] - v;
  int node = b * 256 + t;
  if (node < N) { row_start[node] = lo + excl; deg[node] = v; }
  cur[t] = lo + excl;
  __syncthreads();
  for (int e = lo + t; e < hi; e += 256) {
    u32 p = buf[e];
    int d8 = (p >> 16) & 255;
    int pos = atomicAdd(&cur[d8], 1);
    csr[pos] = p & 0xffff;
  }
}

// ---------------- GEMM: A[M,128] x B[128,ncol] -> bf16 C ----------------
template <bool EPI, bool AFLAG>
__global__ __launch_bounds__(256) void k_gemm(const void* __restrict__ A,
                                              const float* __restrict__ B,
                                              const float* __restrict__ scale,
                                              const float* __restrict__ shift,
                                              u16* __restrict__ C, int M, int ncoltot,
                                              const int* __restrict__ flags) {
  constexpr int K = 128, KP = K + 4;
  __shared__ float As[64 * KP];
  __shared__ float Bs[K * 64];
  int t = threadIdx.x;
  int row0 = blockIdx.x * 64, co = blockIdx.y * 64;
  bool af32 = AFLAG ? (flags[0] != 0) : false;
  for (int i = t; i < K * 16; i += 256) {
    int r = i >> 4, c4 = i & 15;
    ((float4*)Bs)[r * 16 + c4] = ((const float4*)B)[(size_t)r * (ncoltot >> 2) + (co >> 2) + c4];
  }
  for (int i = t; i < 64 * 32; i += 256) {
    int r = i >> 5, c4 = i & 31;
    float4 v = make_float4(0.f, 0.f, 0.f, 0.f);
    int row = row0 + r;
    if (row < M) {
      if (af32) {
        v = ((const float4*)A)[(size_t)row * 32 + c4];
      } else {
        uint2 p = ((const uint2*)A)[(size_t)row * 32 + c4];
        v.x = bflo(p.x); v.y = bfhi(p.x); v.z = bflo(p.y); v.w = bfhi(p.y);
      }
      if (EPI) {
        int c = c4 * 4;
        v.x = fmaf(v.x, scale[c],     shift[c]);     v.x = v.x > 0.f ? v.x : __expf(v.x) - 1.f;
        v.y = fmaf(v.y, scale[c + 1], shift[c + 1]); v.y = v.y > 0.f ? v.y : __expf(v.y) - 1.f;
        v.z = fmaf(v.z, scale[c + 2], shift[c + 2]); v.z = v.z > 0.f ? v.z : __expf(v.z) - 1.f;
        v.w = fmaf(v.w, scale[c + 3], shift[c + 3]); v.w = v.w > 0.f ? v.w : __expf(v.w) - 1.f;
      }
    }
    *(float4*)&As[r * KP + c4 * 4] = v;
  }
  __syncthreads();
  int tx = t & 7, ty = t >> 3;
  int c0 = tx * 8, r0 = ty * 2;
  float acc[2][8];
#pragma unroll
  for (int i = 0; i < 2; i++) for (int j = 0; j < 8; j++) acc[i][j] = 0.f;
#pragma unroll 4
  for (int k = 0; k < K; k++) {
    float4 b0 = *(const float4*)&Bs[k * 64 + c0];
    float4 b1 = *(const float4*)&Bs[k * 64 + c0 + 4];
    float a0 = As[r0 * KP + k];
    float a1 = As[(r0 + 1) * KP + k];
    acc[0][0] = fmaf(a0, b0.x, acc[0][0]); acc[0][1] = fmaf(a0, b0.y, acc[0][1]);
    acc[0][2] = fmaf(a0, b0.z, acc[0][2]); acc[0][3] = fmaf(a0, b0.w, acc[0][3]);
    acc[0][4] = fmaf(a0, b1.x, acc[0][4]); acc[0][5] = fmaf(a0, b1.y, acc[0][5]);
    acc[0][6] = fmaf(a0, b1.z, acc[0][6]); acc[0][7] = fmaf(a0, b1.w, acc[0][7]);
    acc[1][0] = fmaf(a1, b0.x, acc[1][0]); acc[1][1] = fmaf(a1, b0.y, acc[1][1]);
    acc[1][2] = fmaf(a1, b0.z, acc[1][2]); acc[1][3] = fmaf(a1, b0.w, acc[1][3]);
    acc[1][4] = fmaf(a1, b1.x, acc[1][4]); acc[1][5] = fmaf(a1, b1.y, acc[1][5]);
    acc[1][6] = fmaf(a1, b1.z, acc[1][6]); acc[1][7] = fmaf(a1, b1.w, acc[1][7]);
  }
#pragma unroll
  for (int i = 0; i < 2; i++) {
    int row = row0 + r0 + i;
    if (row < M) {
      u32* cp = (u32*)&C[(size_t)row * ncoltot + co + c0];
      cp[0] = pack2(acc[i][0], acc[i][1]);
      cp[1] = pack2(acc[i][2], acc[i][3]);
      cp[2] = pack2(acc[i][4], acc[i][5]);
      cp[3] = pack2(acc[i][6], acc[i][7]);
    }
  }
}

// ---------------- per-node attention coefficients, layer 1 ----------------
__global__ void k_alpha1(const u16* __restrict__ h1b, const float* __restrict__ a1s,
                         const float* __restrict__ a1d, float* __restrict__ as_out,
                         float* __restrict__ ad_out, int N) {
  int idx = blockIdx.x * 256 + threadIdx.x;
  if (idx >= N * HEADS) return;
  int n = idx >> 3, h = idx & 7;
  const u32* hp = (const u32*)&h1b[((size_t)n << 7) + (h << 4)];
  float s = 0.f, d = 0.f;
#pragma unroll
  for (int q = 0; q < 8; q++) {
    u32 p = hp[q];
    float v0 = bflo(p), v1 = bfhi(p);
    int b = (h << 4) + q * 2;
    s = fmaf(v0, a1s[b], s); s = fmaf(v1, a1s[b + 1], s);
    d = fmaf(v0, a1d[b], d); d = fmaf(v1, a1d[b + 1], d);
  }
  as_out[idx] = s; ad_out[idx] = d;
}

// ---------------- aggregation layer 1 (self-loop handled explicitly) --------
__global__ __launch_bounds__(256) void k_agg1(const u16* __restrict__ h1b,
                                              const float* __restrict__ as_,
                                              const float* __restrict__ ad_,
                                              const int* __restrict__ csr,
                                              const int* __restrict__ row_start,
                                              const int* __restrict__ deg,
                                              const float* __restrict__ b1,
                                              u16* __restrict__ out, int N) {
  int w = threadIdx.x >> 6;
  int node = blockIdx.x * 4 + w;
  if (node >= N) return;
  int l = threadIdx.x & 63;
  int head = l >> 3;
  int st = row_start[node], cnt = deg[node];
  float ad = ad_[(node << 3) | head];
  float s = 0.f, a0 = 0.f, a1 = 0.f;
  const u32* h32 = (const u32*)h1b;
  int j = 0;
  for (; j + 4 <= cnt; j += 4) {
    int s0 = csr[st + j], s1 = csr[st + j + 1], s2 = csr[st + j + 2], s3 = csr[st + j + 3];
    float e0 = as_[(s0 << 3) | head], e1 = as_[(s1 << 3) | head];
    float e2 = as_[(s2 << 3) | head], e3 = as_[(s3 << 3) | head];
    u32 h0 = h32[(s0 << 6) | l], h1v = h32[(s1 << 6) | l];
    u32 h2v = h32[(s2 << 6) | l], h3 = h32[(s3 << 6) | l];
    e0 += ad; e0 = fmaxf(e0, 0.2f * e0); float p0 = __expf(e0);
    e1 += ad; e1 = fmaxf(e1, 0.2f * e1); float p1 = __expf(e1);
    e2 += ad; e2 = fmaxf(e2, 0.2f * e2); float p2 = __expf(e2);
    e3 += ad; e3 = fmaxf(e3, 0.2f * e3); float p3 = __expf(e3);
    s += (p0 + p1) + (p2 + p3);
    a0 = fmaf(p0, bflo(h0), a0);  a1 = fmaf(p0, bfhi(h0), a1);
    a0 = fmaf(p1, bflo(h1v), a0); a1 = fmaf(p1, bfhi(h1v), a1);
    a0 = fmaf(p2, bflo(h2v), a0); a1 = fmaf(p2, bfhi(h2v), a1);
    a0 = fmaf(p3, bflo(h3), a0);  a1 = fmaf(p3, bfhi(h3), a1);
  }
  for (; j < cnt; j++) {
    int s0 = csr[st + j];
    float e0 = as_[(s0 << 3) | head] + ad;
    e0 = fmaxf(e0, 0.2f * e0);
    float p0 = __expf(e0);
    u32 h0 = h32[(s0 << 6) | l];
    s += p0;
    a0 = fmaf(p0, bflo(h0), a0); a1 = fmaf(p0, bfhi(h0), a1);
  }
  { // self-loop
    float e0 = as_[(node << 3) | head] + ad;
    e0 = fmaxf(e0, 0.2f * e0);
    float p0 = __expf(e0);
    u32 h0 = h32[((size_t)node << 6) | l];
    s += p0;
    a0 = fmaf(p0, bflo(h0), a0); a1 = fmaf(p0, bfhi(h0), a1);
  }
  float inv = 1.f / (s + 1e-16f);
  int c0 = l * 2;
  ((u32*)out)[((size_t)node << 6) + l] =
      pack2(fmaf(a0, inv, b1[c0]), fmaf(a1, inv, b1[c0 + 1]));
}

// ---------------- batch norm stats ----------------
__global__ void k_bnstat(const u16* __restrict__ h, float* __restrict__ gsum,
                         float* __restrict__ gsq, int N) {
  __shared__ float ts[256], tq[256];
  int t = threadIdx.x, col = t & 127, rr = t >> 7;
  int row0 = blockIdx.x * 128;
  float s = 0.f, q = 0.f;
  for (int r = rr; r < 128; r += 2) {
    int row = row0 + r;
    if (row < N) {
      float v = bf2f(h[((size_t)row << 7) + col]);
      s += v; q = fmaf(v, v, q);
    }
  }
  ts[t] = s; tq[t] = q; __syncthreads();
  if (t < 128) {
    atomicAdd(&gsum[t], ts[t] + ts[t + 128]);
    atomicAdd(&gsq[t], tq[t] + tq[t + 128]);
  }
}

__global__ void k_bnfin(const float* __restrict__ gsum, const float* __restrict__ gsq,
                        const float* __restrict__ gamma, const float* __restrict__ beta,
                        float* __restrict__ scale, float* __restrict__ shift, int N) {
  int t = threadIdx.x;
  if (t >= 128) return;
  float mu = gsum[t] / (float)N;
  float var = fmaxf(gsq[t] / (float)N - mu * mu, 0.f);
  float s = gamma[t] * rsqrtf(var + 1e-5f);
  scale[t] = s;
  shift[t] = beta[t] - mu * s;
}

// ---------------- per-node attention coefficients, layer 2 ----------------
__global__ void k_alpha2(const u16* __restrict__ h2b, const float* __restrict__ a2s,
                         const float* __restrict__ a2d, float* __restrict__ as_out,
                         float* __restrict__ ad_out, int N) {
  int w = threadIdx.x >> 6;
  int node = blockIdx.x * 4 + w;
  if (node >= N) return;
  int l = threadIdx.x & 63;
  float v = bf2f(h2b[((size_t)node << 6) + l]);
  float vs = v * a2s[l], vd = v * a2d[l];
  for (int o = 32; o; o >>= 1) { vs += __shfl_xor(vs, o, 64); vd += __shfl_xor(vd, o, 64); }
  if (l == 0) { as_out[node] = vs; ad_out[node] = vd; }
}

// ---------------- aggregation layer 2 -> output ----------------
__global__ __launch_bounds__(256) void k_agg2(const u16* __restrict__ h2b,
                                              const float* __restrict__ as_,
                                              const float* __restrict__ ad_,
                                              const int* __restrict__ csr,
                                              const int* __restrict__ row_start,
                                              const int* __restrict__ deg,
                                              const float* __restrict__ b2,
                                              void* __restrict__ out,
                                              const int* __restrict__ flags, int N) {
  int w = threadIdx.x >> 6;
  int node = blockIdx.x * 4 + w;
  if (node >= N) return;
  int l = threadIdx.x & 63;
  int st = row_start[node], cnt = deg[node];
  float ad = ad_[node];
  float s = 0.f, a = 0.f;
  int j = 0;
  for (; j + 4 <= cnt; j += 4) {
    int s0 = csr[st + j], s1 = csr[st + j + 1], s2 = csr[st + j + 2], s3 = csr[st + j + 3];
    float e0 = as_[s0], e1 = as_[s1], e2 = as_[s2], e3 = as_[s3];
    u16 v0 = h2b[(s0 << 6) | l], v1 = h2b[(s1 << 6) | l];
    u16 v2 = h2b[(s2 << 6) | l], v3 = h2b[(s3 << 6) | l];
    e0 += ad; e0 = fmaxf(e0, 0.2f * e0); float p0 = __expf(e0);
    e1 += ad; e1 = fmaxf(e1, 0.2f * e1); float p1 = __expf(e1);
    e2 += ad; e2 = fmaxf(e2, 0.2f * e2); float p2 = __expf(e2);
    e3 += ad; e3 = fmaxf(e3, 0.2f * e3); float p3 = __expf(e3);
    s += (p0 + p1) + (p2 + p3);
    a = fmaf(p0, bf2f(v0), a); a = fmaf(p1, bf2f(v1), a);
    a = fmaf(p2, bf2f(v2), a); a = fmaf(p3, bf2f(v3), a);
  }
  for (; j < cnt; j++) {
    int s0 = csr[st + j];
    float e0 = as_[s0] + ad;
    e0 = fmaxf(e0, 0.2f * e0);
    float p0 = __expf(e0);
    s += p0;
    a = fmaf(p0, bf2f(h2b[(s0 << 6) | l]), a);
  }
  { // self-loop
    float e0 = as_[node] + ad;
    e0 = fmaxf(e0, 0.2f * e0);
    float p0 = __expf(e0);
    s += p0;
    a = fmaf(p0, bf2f(h2b[((size_t)node << 6) | l]), a);
  }
  float r = a / (s + 1e-16f) + b2[l];
  size_t idx = ((size_t)node << 6) + l;
  if (flags[0]) ((float*)out)[idx] = r;
  else          ((u16*)out)[idx] = f2bf(r);
}

extern "C" void kernel_launch(void* const* d_in, const int* in_sizes, int n_in,
                              void* d_out, int out_size, void* d_ws, size_t ws_size,
                              hipStream_t stream) {
  const void* x   = d_in[0];
  const int*  ei  = (const int*)d_in[1];
  const void* W1  = d_in[2];
  const void* a1s = d_in[3];
  const void* a1d = d_in[4];
  const void* b1  = d_in[5];
  const void* gam = d_in[6];
  const void* bet = d_in[7];
  const void* W2  = d_in[8];
  const void* a2s = d_in[9];
  const void* a2d = d_in[10];
  const void* b2  = d_in[11];

  char* ws = (char*)d_ws;
  size_t off = 0;
  auto alloc = [&](size_t bytes) -> void* {
    void* p = ws + off;
    off += (bytes + 255) & ~(size_t)255;
    return p;
  };
  int* flags = (int*)alloc(256);
  // zero-init region: totals[196] | gsum[128] | gsq[128]
  char* zreg = (char*)alloc(2048);
  int* totals = (int*)zreg;
  float* gsum = (float*)(zreg + 1024);
  float* gsq  = gsum + 128;
  int* H  = (int*)alloc((size_t)NBK * NBLK * 4);
  int* P  = (int*)alloc((size_t)NBK * NBLK * 4);
  int* bucketBase = (int*)alloc(1024);
  u32* ebuf = (u32*)alloc((size_t)N_EDGES * 4);
  int* csr = (int*)alloc((size_t)N_EDGES * 4);
  int* row_start = (int*)alloc((size_t)N_NODES * 4);
  int* deg = (int*)alloc((size_t)N_NODES * 4);
  float* smallf = (float*)alloc(25408 * 4);
  float* a1sf = smallf;        float* a1df = smallf + 128;
  float* b1f  = smallf + 256;  float* gamf = smallf + 384;
  float* betf = smallf + 512;  float* a2sf = smallf + 640;
  float* a2df = smallf + 704;  float* b2f  = smallf + 768;
  float* W1f  = smallf + 832;  float* W2f  = smallf + 17216;
  u16* h1b  = (u16*)alloc((size_t)N_NODES * 128 * 2);
  u16* h1ob = (u16*)alloc((size_t)N_NODES * 128 * 2);
  u16* h2b  = (u16*)alloc((size_t)N_NODES * 64 * 2);
  float* al1s = (float*)alloc((size_t)N_NODES * 8 * 4);
  float* al1d = (float*)alloc((size_t)N_NODES * 8 * 4);
  float* scale = (float*)alloc(512);
  float* shift = (float*)alloc(512);
  float* al2s = (float*)alloc((size_t)N_NODES * 4);
  float* al2d = (float*)alloc((size_t)N_NODES * 4);
  if (off > ws_size) return;

  hipMemsetAsync(zreg, 0, 2048, stream);
  k_detect<<<1, 256, 0, stream>>>((const u16*)x, (const u32*)ei, flags);
  k_convsmall<<<100, 256, 0, stream>>>(a1s, a1d, b1, gam, bet, a2s, a2d, b2, W1, W2,
                                       smallf, flags);

  // ---- CSR build (no global atomics on the edge path) ----
  k_hist<<<NBLK, 256, 0, stream>>>(ei, H, totals, flags);
  k_scan_tot<<<1, 256, 0, stream>>>(totals, bucketBase);
  k_scan_blk<<<NBK, 256, 0, stream>>>(H, bucketBase, P);
  k_bucket<<<NBLK, 256, 0, stream>>>(ei, P, ebuf, flags);
  k_csr<<<NBK, 256, 0, stream>>>(ebuf, bucketBase, row_start, deg, csr, N_NODES);

  // ---- layer 1 ----
  dim3 g1((N_NODES + 63) / 64, 2);
  k_gemm<false, true><<<g1, 256, 0, stream>>>(x, W1f, nullptr, nullptr, h1b,
                                              N_NODES, 128, flags);
  k_alpha1<<<(N_NODES * HEADS + 255) / 256, 256, 0, stream>>>(h1b, a1sf, a1df,
                                                              al1s, al1d, N_NODES);
  k_agg1<<<(N_NODES + 3) / 4, 256, 0, stream>>>(h1b, al1s, al1d, csr, row_start, deg,
                                                b1f, h1ob, N_NODES);

  // ---- BN ----
  k_bnstat<<<(N_NODES + 127) / 128, 256, 0, stream>>>(h1ob, gsum, gsq, N_NODES);
  k_bnfin<<<1, 128, 0, stream>>>(gsum, gsq, gamf, betf, scale, shift, N_NODES);

  // ---- layer 2 ----
  dim3 g2((N_NODES + 63) / 64, 1);
  k_gemm<true, false><<<g2, 256, 0, stream>>>(h1ob, W2f, scale, shift, h2b,
                                              N_NODES, 64, flags);
  k_alpha2<<<(N_NODES + 3) / 4, 256, 0, stream>>>(h2b, a2sf, a2df, al2s, al2d, N_NODES);
  k_agg2<<<(N_NODES + 3) / 4, 256, 0, stream>>>(h2b, al2s, al2d, csr, row_start, deg,
                                                b2f, d_out, flags, N_NODES);
}

// Round 5
// 350.027 us; speedup vs baseline: 2.2225x; 1.1452x over previous
//
#include <hip/hip_runtime.h>
#include <hip/hip_bf16.h>

#define N_NODES 50000
#define N_EDGES 1600000
#define HEADS 8
#define NBK 196   // buckets: dst>>8
#define NBLK 196  // edge tiles: 196*8192 >= 1.6M

typedef unsigned short u16;
typedef unsigned int u32;
typedef __attribute__((ext_vector_type(8))) short bf16x8;
typedef __attribute__((ext_vector_type(4))) float f32x4;

__device__ __forceinline__ float bf2f(u16 u) {
  union { u32 i; float f; } v; v.i = ((u32)u) << 16; return v.f;
}
__device__ __forceinline__ float bflo(u32 p) {
  union { u32 i; float f; } v; v.i = p << 16; return v.f;
}
__device__ __forceinline__ float bfhi(u32 p) {
  union { u32 i; float f; } v; v.i = p & 0xffff0000u; return v.f;
}
__device__ __forceinline__ u16 f2bf(float f) {
  union { float f; u32 i; } v; v.f = f;
  u32 r = v.i + 0x7fff + ((v.i >> 16) & 1);  // RNE
  return (u16)(r >> 16);
}
__device__ __forceinline__ u32 pack2(float a, float b) {
  return (u32)f2bf(a) | ((u32)f2bf(b) << 16);
}

// ---------------- dtype auto-detection ----------------
__global__ void k_detect(const u16* __restrict__ x, const u32* __restrict__ ei,
                         int* __restrict__ flags) {
  __shared__ int cbig, cnz;
  if (threadIdx.x == 0) { cbig = 0; cnz = 0; }
  __syncthreads();
  int lb = 0, ln = 0;
  for (int i = threadIdx.x; i < 4096; i += 256) {
    int ex = (x[i] >> 7) & 0xff;
    lb += (ex >= 140);
    if (i < 2048) ln += (ei[2 * i + 1] != 0);
  }
  atomicAdd(&cbig, lb); atomicAdd(&cnz, ln);
  __syncthreads();
  if (threadIdx.x == 0) {
    flags[0] = (cbig > 16) ? 1 : 0;   // 1: floats are fp32
    flags[1] = (cnz == 0) ? 1 : 0;    // 1: edge_index is int64
  }
}

// ---------------- converter: vectors -> fp32, W1/W2 -> transposed bf16 -------
// smallf: a1s[0,128) a1d[128) b1[256) gam[384) bet[512) a2s[640) a2d[704) b2[768)
__global__ void k_convsmall(const void* a1s, const void* a1d, const void* b1,
                            const void* gam, const void* bet, const void* a2s,
                            const void* a2d, const void* b2, const void* W1,
                            const void* W2, float* __restrict__ smallf,
                            u16* __restrict__ w1t, u16* __restrict__ w2t,
                            const int* __restrict__ flags) {
  int i = blockIdx.x * 256 + threadIdx.x;
  if (i >= 25408) return;
  bool f32 = flags[0] != 0;
  auto ld = [&](const void* p, int off) -> float {
    return f32 ? ((const float*)p)[off] : bf2f(((const u16*)p)[off]);
  };
  if (i >= 17216) {            // W2T[n][k], n<64, k<128  <- W2[k*64+n]
    int j = i - 17216, n = j >> 7, k = j & 127;
    w2t[j] = f2bf(ld(W2, k * 64 + n));
  } else if (i >= 832) {       // W1T[n][k], n<128, k<128 <- W1[k*128+n]
    int j = i - 832, n = j >> 7, k = j & 127;
    w1t[j] = f2bf(ld(W1, k * 128 + n));
  } else {
    const void* src; int off;
    if (i >= 768)      { src = b2;  off = i - 768; }
    else if (i >= 704) { src = a2d; off = i - 704; }
    else if (i >= 640) { src = a2s; off = i - 640; }
    else if (i >= 512) { src = bet; off = i - 512; }
    else if (i >= 384) { src = gam; off = i - 384; }
    else if (i >= 256) { src = b1;  off = i - 256; }
    else if (i >= 128) { src = a1d; off = i - 128; }
    else               { src = a1s; off = i; }
    smallf[i] = ld(src, off);
  }
}

// ---------------- CSR build (atomic-free two-level counting sort) ----------
__global__ __launch_bounds__(256) void k_hist(const int* __restrict__ ei,
                                              int* __restrict__ H,
                                              int* __restrict__ totals,
                                              const int* __restrict__ flags) {
  __shared__ int hist[NBK];
  int t = threadIdx.x, blk = blockIdx.x;
  for (int i = t; i < NBK; i += 256) hist[i] = 0;
  __syncthreads();
  bool i64 = flags[1] != 0;
  int base = blk * 8192;
  for (int k = 0; k < 32; k++) {
    int e = base + k * 256 + t;
    if (e < N_EDGES) {
      int d = i64 ? ei[2 * (N_EDGES + e)] : ei[N_EDGES + e];
      atomicAdd(&hist[d >> 8], 1);
    }
  }
  __syncthreads();
  for (int i = t; i < NBK; i += 256) {
    H[i * NBLK + blk] = hist[i];
    atomicAdd(&totals[i], hist[i]);
  }
}

__global__ void k_scan_tot(const int* __restrict__ totals, int* __restrict__ bucketBase) {
  __shared__ int tmp[256];
  int t = threadIdx.x;
  int v = (t < NBK) ? totals[t] : 0;
  tmp[t] = v; __syncthreads();
  for (int o = 1; o < 256; o <<= 1) {
    int x = (t >= o) ? tmp[t - o] : 0; __syncthreads();
    tmp[t] += x; __syncthreads();
  }
  if (t < NBK) bucketBase[t] = tmp[t] - v;
  if (t == NBK - 1) bucketBase[NBK] = tmp[t];
}

__global__ void k_scan_blk(const int* __restrict__ H, const int* __restrict__ bucketBase,
                           int* __restrict__ P) {
  __shared__ int tmp[256];
  int t = threadIdx.x, b = blockIdx.x;
  int v = (t < NBLK) ? H[b * NBLK + t] : 0;
  tmp[t] = v; __syncthreads();
  for (int o = 1; o < 256; o <<= 1) {
    int x = (t >= o) ? tmp[t - o] : 0; __syncthreads();
    tmp[t] += x; __syncthreads();
  }
  if (t < NBLK) P[b * NBLK + t] = bucketBase[b] + tmp[t] - v;
}

__global__ __launch_bounds__(256) void k_bucket(const int* __restrict__ ei,
                                                const int* __restrict__ P,
                                                u32* __restrict__ buf,
                                                const int* __restrict__ flags) {
  __shared__ int cur[NBK];
  int t = threadIdx.x, blk = blockIdx.x;
  for (int i = t; i < NBK; i += 256) cur[i] = P[i * NBLK + blk];
  __syncthreads();
  bool i64 = flags[1] != 0;
  int base = blk * 8192;
  for (int k = 0; k < 32; k++) {
    int e = base + k * 256 + t;
    if (e < N_EDGES) {
      int s = i64 ? ei[2 * e] : ei[e];
      int d = i64 ? ei[2 * (N_EDGES + e)] : ei[N_EDGES + e];
      int pos = atomicAdd(&cur[d >> 8], 1);
      buf[pos] = ((u32)(d & 255) << 16) | (u32)s;
    }
  }
}

__global__ __launch_bounds__(256) void k_csr(const u32* __restrict__ buf,
                                             const int* __restrict__ bucketBase,
                                             int* __restrict__ row_start,
                                             int* __restrict__ deg,
                                             int* __restrict__ csr, int N) {
  __shared__ int cnt[256], scn[256], cur[256];
  int b = blockIdx.x, t = threadIdx.x;
  int lo = bucketBase[b], hi = bucketBase[b + 1];
  cnt[t] = 0; __syncthreads();
  for (int e = lo + t; e < hi; e += 256) atomicAdd(&cnt[(buf[e] >> 16) & 255], 1);
  __syncthreads();
  int v = cnt[t];
  scn[t] = v; __syncthreads();
  for (int o = 1; o < 256; o <<= 1) {
    int x = (t >= o) ? scn[t - o] : 0; __syncthreads();
    scn[t] += x; __syncthreads();
  }
  int excl = scn[t] - v;
  int node = b * 256 + t;
  if (node < N) { row_start[node] = lo + excl; deg[node] = v; }
  cur[t] = lo + excl;
  __syncthreads();
  for (int e = lo + t; e < hi; e += 256) {
    u32 p = buf[e];
    int pos = atomicAdd(&cur[(p >> 16) & 255], 1);
    csr[pos] = p & 0xffff;
  }
}

// ---------------- MFMA GEMM: A[M,128] x BT[NCOLS,128] -> bf16 C[M,NCOLS] ----
// Tile 64 rows x NCOLS cols, K=128, 4 waves (wave w: rows w*16..w*16+16).
template <int NCOLS, bool EPI, bool AFLAG>
__global__ __launch_bounds__(256) void k_gemm_mfma(const void* __restrict__ A,
                                                   const u16* __restrict__ BT,
                                                   const float* __restrict__ scale,
                                                   const float* __restrict__ shift,
                                                   u16* __restrict__ C, int M,
                                                   const int* __restrict__ flags) {
  constexpr int KP = 136;  // padded K stride (u16): +8 keeps b128 16B-aligned, 2-way banks
  constexpr int NT = NCOLS / 16;
  __shared__ u16 As[64 * KP];
  __shared__ u16 Bs[NCOLS * KP];
  int t = threadIdx.x;
  int row0 = blockIdx.x * 64;
  bool af32 = AFLAG ? (flags[0] != 0) : false;

  // stage B: BT[n][k] -> Bs[n*KP + k], 16B chunks
  for (int i = t; i < NCOLS * 16; i += 256) {
    int n = i >> 4, q = i & 15;
    *(uint4*)&Bs[n * KP + q * 8] = ((const uint4*)BT)[n * 16 + q];
  }
  // stage A: 4-channel groups, pack to bf16 (+ BN/ELU for layer 2)
  for (int i = t; i < 64 * 32; i += 256) {
    int r = i >> 5, c4 = i & 31;
    int row = row0 + r;
    uint2 pk = make_uint2(0u, 0u);
    if (row < M) {
      if (EPI) {  // A is bf16 h1o; apply BN+ELU in fp32, repack
        uint2 p = ((const uint2*)A)[(size_t)row * 32 + c4];
        int c = c4 * 4;
        float v0 = bflo(p.x), v1 = bfhi(p.x), v2 = bflo(p.y), v3 = bfhi(p.y);
        v0 = fmaf(v0, scale[c],     shift[c]);     v0 = v0 > 0.f ? v0 : __expf(v0) - 1.f;
        v1 = fmaf(v1, scale[c + 1], shift[c + 1]); v1 = v1 > 0.f ? v1 : __expf(v1) - 1.f;
        v2 = fmaf(v2, scale[c + 2], shift[c + 2]); v2 = v2 > 0.f ? v2 : __expf(v2) - 1.f;
        v3 = fmaf(v3, scale[c + 3], shift[c + 3]); v3 = v3 > 0.f ? v3 : __expf(v3) - 1.f;
        pk.x = pack2(v0, v1); pk.y = pack2(v2, v3);
      } else if (af32) {
        float4 v = ((const float4*)A)[(size_t)row * 32 + c4];
        pk.x = pack2(v.x, v.y); pk.y = pack2(v.z, v.w);
      } else {
        pk = ((const uint2*)A)[(size_t)row * 32 + c4];
      }
    }
    *(uint2*)&As[r * KP + c4 * 4] = pk;
  }
  __syncthreads();

  int lane = t & 63, w = t >> 6;
  int m = lane & 15, quad = lane >> 4;
  f32x4 acc[NT];
#pragma unroll
  for (int nt = 0; nt < NT; nt++) acc[nt] = (f32x4)(0.f);
  const u16* aBase = &As[(w * 16 + m) * KP + quad * 8];
  const u16* bBase = &Bs[m * KP + quad * 8];
#pragma unroll
  for (int ks = 0; ks < 4; ks++) {
    bf16x8 af = *(const bf16x8*)(aBase + ks * 32);
#pragma unroll
    for (int nt = 0; nt < NT; nt++) {
      bf16x8 bf = *(const bf16x8*)(bBase + nt * 16 * KP + ks * 32);
      acc[nt] = __builtin_amdgcn_mfma_f32_16x16x32_bf16(af, bf, acc[nt], 0, 0, 0);
    }
  }
  int orow0 = row0 + w * 16 + quad * 4;
#pragma unroll
  for (int nt = 0; nt < NT; nt++) {
#pragma unroll
    for (int r = 0; r < 4; r++) {
      int row = orow0 + r;
      if (row < M) C[(size_t)row * NCOLS + nt * 16 + m] = f2bf(acc[nt][r]);
    }
  }
}

// ---------------- per-node attention coefficients, layer 1 ----------------
__global__ void k_alpha1(const u16* __restrict__ h1b, const float* __restrict__ a1s,
                         const float* __restrict__ a1d, float* __restrict__ as_out,
                         float* __restrict__ ad_out, int N) {
  int idx = blockIdx.x * 256 + threadIdx.x;
  if (idx >= N * HEADS) return;
  int n = idx >> 3, h = idx & 7;
  const u32* hp = (const u32*)&h1b[((size_t)n << 7) + (h << 4)];
  float s = 0.f, d = 0.f;
#pragma unroll
  for (int q = 0; q < 8; q++) {
    u32 p = hp[q];
    float v0 = bflo(p), v1 = bfhi(p);
    int b = (h << 4) + q * 2;
    s = fmaf(v0, a1s[b], s); s = fmaf(v1, a1s[b + 1], s);
    d = fmaf(v0, a1d[b], d); d = fmaf(v1, a1d[b + 1], d);
  }
  as_out[idx] = s; ad_out[idx] = d;
}

// ---------------- aggregation layer 1: scalarized addressing --------------
__global__ __launch_bounds__(256) void k_agg1(const u16* __restrict__ h1b,
                                              const float* __restrict__ as_,
                                              const float* __restrict__ ad_,
                                              const int* __restrict__ csr,
                                              const int* __restrict__ row_start,
                                              const int* __restrict__ deg,
                                              const float* __restrict__ b1,
                                              u16* __restrict__ out, int N) {
  int node = blockIdx.x * 4 + (threadIdx.x >> 6);
  if (node >= N) return;
  int l = threadIdx.x & 63;
  int head = l >> 3;
  int node_u = __builtin_amdgcn_readfirstlane(node);
  int st = __builtin_amdgcn_readfirstlane(row_start[node_u]);
  int cnt = __builtin_amdgcn_readfirstlane(deg[node_u]);
  const int* cp = csr + st;
  const u32* h32 = (const u32*)h1b;
  float ad = ad_[(node_u << 3) | head];
  float s = 0.f, a0 = 0.f, a1 = 0.f;
  int j = 0;
  for (; j + 4 <= cnt; j += 4) {
    int s0 = cp[j], s1 = cp[j + 1], s2 = cp[j + 2], s3 = cp[j + 3];
    float e0 = (as_ + (s0 << 3))[head], e1 = (as_ + (s1 << 3))[head];
    float e2 = (as_ + (s2 << 3))[head], e3 = (as_ + (s3 << 3))[head];
    u32 h0 = (h32 + (s0 << 6))[l], h1v = (h32 + (s1 << 6))[l];
    u32 h2v = (h32 + (s2 << 6))[l], h3 = (h32 + (s3 << 6))[l];
    e0 += ad; e0 = fmaxf(e0, 0.2f * e0); float p0 = __expf(e0);
    e1 += ad; e1 = fmaxf(e1, 0.2f * e1); float p1 = __expf(e1);
    e2 += ad; e2 = fmaxf(e2, 0.2f * e2); float p2 = __expf(e2);
    e3 += ad; e3 = fmaxf(e3, 0.2f * e3); float p3 = __expf(e3);
    s += (p0 + p1) + (p2 + p3);
    a0 = fmaf(p0, bflo(h0), a0);  a1 = fmaf(p0, bfhi(h0), a1);
    a0 = fmaf(p1, bflo(h1v), a0); a1 = fmaf(p1, bfhi(h1v), a1);
    a0 = fmaf(p2, bflo(h2v), a0); a1 = fmaf(p2, bfhi(h2v), a1);
    a0 = fmaf(p3, bflo(h3), a0);  a1 = fmaf(p3, bfhi(h3), a1);
  }
  for (; j < cnt; j++) {
    int s0 = cp[j];
    float e0 = (as_ + (s0 << 3))[head] + ad;
    e0 = fmaxf(e0, 0.2f * e0);
    float p0 = __expf(e0);
    u32 h0 = (h32 + (s0 << 6))[l];
    s += p0;
    a0 = fmaf(p0, bflo(h0), a0); a1 = fmaf(p0, bfhi(h0), a1);
  }
  { // self-loop
    float e0 = (as_ + (node_u << 3))[head] + ad;
    e0 = fmaxf(e0, 0.2f * e0);
    float p0 = __expf(e0);
    u32 h0 = (h32 + (node_u << 6))[l];
    s += p0;
    a0 = fmaf(p0, bflo(h0), a0); a1 = fmaf(p0, bfhi(h0), a1);
  }
  float inv = 1.f / (s + 1e-16f);
  int c0 = l * 2;
  ((u32*)out)[((size_t)node_u << 6) + l] =
      pack2(fmaf(a0, inv, b1[c0]), fmaf(a1, inv, b1[c0 + 1]));
}

// ---------------- batch norm ----------------
__global__ void k_bnstat(const u16* __restrict__ h, float* __restrict__ gsum,
                         float* __restrict__ gsq, int N) {
  __shared__ float ts[256], tq[256];
  int t = threadIdx.x, col = t & 127, rr = t >> 7;
  int row0 = blockIdx.x * 128;
  float s = 0.f, q = 0.f;
  for (int r = rr; r < 128; r += 2) {
    int row = row0 + r;
    if (row < N) {
      float v = bf2f(h[((size_t)row << 7) + col]);
      s += v; q = fmaf(v, v, q);
    }
  }
  ts[t] = s; tq[t] = q; __syncthreads();
  if (t < 128) {
    atomicAdd(&gsum[t], ts[t] + ts[t + 128]);
    atomicAdd(&gsq[t], tq[t] + tq[t + 128]);
  }
}

__global__ void k_bnfin(const float* __restrict__ gsum, const float* __restrict__ gsq,
                        const float* __restrict__ gamma, const float* __restrict__ beta,
                        float* __restrict__ scale, float* __restrict__ shift, int N) {
  int t = threadIdx.x;
  if (t >= 128) return;
  float mu = gsum[t] / (float)N;
  float var = fmaxf(gsq[t] / (float)N - mu * mu, 0.f);
  float s = gamma[t] * rsqrtf(var + 1e-5f);
  scale[t] = s;
  shift[t] = beta[t] - mu * s;
}

// ---------------- per-node attention coefficients, layer 2 ----------------
__global__ void k_alpha2(const u16* __restrict__ h2b, const float* __restrict__ a2s,
                         const float* __restrict__ a2d, float* __restrict__ as_out,
                         float* __restrict__ ad_out, int N) {
  int w = threadIdx.x >> 6;
  int node = blockIdx.x * 4 + w;
  if (node >= N) return;
  int l = threadIdx.x & 63;
  float v = bf2f(h2b[((size_t)node << 6) + l]);
  float vs = v * a2s[l], vd = v * a2d[l];
  for (int o = 32; o; o >>= 1) { vs += __shfl_xor(vs, o, 64); vd += __shfl_xor(vd, o, 64); }
  if (l == 0) { as_out[node] = vs; ad_out[node] = vd; }
}

// ---------------- aggregation layer 2 -> output ----------------
__global__ __launch_bounds__(256) void k_agg2(const u16* __restrict__ h2b,
                                              const float* __restrict__ as_,
                                              const float* __restrict__ ad_,
                                              const int* __restrict__ csr,
                                              const int* __restrict__ row_start,
                                              const int* __restrict__ deg,
                                              const float* __restrict__ b2,
                                              void* __restrict__ out,
                                              const int* __restrict__ flags, int N) {
  int node = blockIdx.x * 4 + (threadIdx.x >> 6);
  if (node >= N) return;
  int l = threadIdx.x & 63;
  int node_u = __builtin_amdgcn_readfirstlane(node);
  int st = __builtin_amdgcn_readfirstlane(row_start[node_u]);
  int cnt = __builtin_amdgcn_readfirstlane(deg[node_u]);
  const int* cp = csr + st;
  float ad = ad_[node_u];
  float s = 0.f, a = 0.f;
  int j = 0;
  for (; j + 4 <= cnt; j += 4) {
    int s0 = cp[j], s1 = cp[j + 1], s2 = cp[j + 2], s3 = cp[j + 3];
    float e0 = as_[s0], e1 = as_[s1], e2 = as_[s2], e3 = as_[s3];
    u16 v0 = (h2b + (s0 << 6))[l], v1 = (h2b + (s1 << 6))[l];
    u16 v2 = (h2b + (s2 << 6))[l], v3 = (h2b + (s3 << 6))[l];
    e0 += ad; e0 = fmaxf(e0, 0.2f * e0); float p0 = __expf(e0);
    e1 += ad; e1 = fmaxf(e1, 0.2f * e1); float p1 = __expf(e1);
    e2 += ad; e2 = fmaxf(e2, 0.2f * e2); float p2 = __expf(e2);
    e3 += ad; e3 = fmaxf(e3, 0.2f * e3); float p3 = __expf(e3);
    s += (p0 + p1) + (p2 + p3);
    a = fmaf(p0, bf2f(v0), a); a = fmaf(p1, bf2f(v1), a);
    a = fmaf(p2, bf2f(v2), a); a = fmaf(p3, bf2f(v3), a);
  }
  for (; j < cnt; j++) {
    int s0 = cp[j];
    float e0 = as_[s0] + ad;
    e0 = fmaxf(e0, 0.2f * e0);
    float p0 = __expf(e0);
    s += p0;
    a = fmaf(p0, bf2f((h2b + (s0 << 6))[l]), a);
  }
  { // self-loop
    float e0 = as_[node_u] + ad;
    e0 = fmaxf(e0, 0.2f * e0);
    float p0 = __expf(e0);
    s += p0;
    a = fmaf(p0, bf2f((h2b + (node_u << 6))[l]), a);
  }
  float r = a / (s + 1e-16f) + b2[l];
  size_t idx = ((size_t)node_u << 6) + l;
  if (flags[0]) ((float*)out)[idx] = r;
  else          ((u16*)out)[idx] = f2bf(r);
}

extern "C" void kernel_launch(void* const* d_in, const int* in_sizes, int n_in,
                              void* d_out, int out_size, void* d_ws, size_t ws_size,
                              hipStream_t stream) {
  const void* x   = d_in[0];
  const int*  ei  = (const int*)d_in[1];
  const void* W1  = d_in[2];
  const void* a1s = d_in[3];
  const void* a1d = d_in[4];
  const void* b1  = d_in[5];
  const void* gam = d_in[6];
  const void* bet = d_in[7];
  const void* W2  = d_in[8];
  const void* a2s = d_in[9];
  const void* a2d = d_in[10];
  const void* b2  = d_in[11];

  char* ws = (char*)d_ws;
  size_t off = 0;
  auto alloc = [&](size_t bytes) -> void* {
    void* p = ws + off;
    off += (bytes + 255) & ~(size_t)255;
    return p;
  };
  int* flags = (int*)alloc(256);
  char* zreg = (char*)alloc(2048);  // totals[196] | gsum[128] | gsq[128]
  int* totals = (int*)zreg;
  float* gsum = (float*)(zreg + 1024);
  float* gsq  = gsum + 128;
  int* H  = (int*)alloc((size_t)NBK * NBLK * 4);
  int* P  = (int*)alloc((size_t)NBK * NBLK * 4);
  int* bucketBase = (int*)alloc(1024);
  u32* ebuf = (u32*)alloc((size_t)N_EDGES * 4);
  int* csr = (int*)alloc((size_t)N_EDGES * 4);
  int* row_start = (int*)alloc((size_t)N_NODES * 4);
  int* deg = (int*)alloc((size_t)N_NODES * 4);
  float* smallf = (float*)alloc(832 * 4);
  float* a1sf = smallf;        float* a1df = smallf + 128;
  float* b1f  = smallf + 256;  float* gamf = smallf + 384;
  float* betf = smallf + 512;  float* a2sf = smallf + 640;
  float* a2df = smallf + 704;  float* b2f  = smallf + 768;
  u16* w1t = (u16*)alloc(16384 * 2);
  u16* w2t = (u16*)alloc(8192 * 2);
  u16* h1b  = (u16*)alloc((size_t)N_NODES * 128 * 2);
  u16* h1ob = (u16*)alloc((size_t)N_NODES * 128 * 2);
  u16* h2b  = (u16*)alloc((size_t)N_NODES * 64 * 2);
  float* al1s = (float*)alloc((size_t)N_NODES * 8 * 4);
  float* al1d = (float*)alloc((size_t)N_NODES * 8 * 4);
  float* scale = (float*)alloc(512);
  float* shift = (float*)alloc(512);
  float* al2s = (float*)alloc((size_t)N_NODES * 4);
  float* al2d = (float*)alloc((size_t)N_NODES * 4);
  if (off > ws_size) return;

  hipMemsetAsync(zreg, 0, 2048, stream);
  k_detect<<<1, 256, 0, stream>>>((const u16*)x, (const u32*)ei, flags);
  k_convsmall<<<100, 256, 0, stream>>>(a1s, a1d, b1, gam, bet, a2s, a2d, b2, W1, W2,
                                       smallf, w1t, w2t, flags);

  // ---- CSR build ----
  k_hist<<<NBLK, 256, 0, stream>>>(ei, H, totals, flags);
  k_scan_tot<<<1, 256, 0, stream>>>(totals, bucketBase);
  k_scan_blk<<<NBK, 256, 0, stream>>>(H, bucketBase, P);
  k_bucket<<<NBLK, 256, 0, stream>>>(ei, P, ebuf, flags);
  k_csr<<<NBK, 256, 0, stream>>>(ebuf, bucketBase, row_start, deg, csr, N_NODES);

  // ---- layer 1 ----
  k_gemm_mfma<128, false, true><<<(N_NODES + 63) / 64, 256, 0, stream>>>(
      x, w1t, nullptr, nullptr, h1b, N_NODES, flags);
  k_alpha1<<<(N_NODES * HEADS + 255) / 256, 256, 0, stream>>>(h1b, a1sf, a1df,
                                                              al1s, al1d, N_NODES);
  k_agg1<<<(N_NODES + 3) / 4, 256, 0, stream>>>(h1b, al1s, al1d, csr, row_start, deg,
                                                b1f, h1ob, N_NODES);

  // ---- BN ----
  k_bnstat<<<(N_NODES + 127) / 128, 256, 0, stream>>>(h1ob, gsum, gsq, N_NODES);
  k_bnfin<<<1, 128, 0, stream>>>(gsum, gsq, gamf, betf, scale, shift, N_NODES);

  // ---- layer 2 ----
  k_gemm_mfma<64, true, false><<<(N_NODES + 63) / 64, 256, 0, stream>>>(
      h1ob, w2t, scale, shift, h2b, N_NODES, flags);
  k_alpha2<<<(N_NODES + 3) / 4, 256, 0, stream>>>(h2b, a2sf, a2df, al2s, al2d, N_NODES);
  k_agg2<<<(N_NODES + 3) / 4, 256, 0, stream>>>(h2b, al2s, al2d, csr, row_start, deg,
                                                b2f, d_out, flags, N_NODES);
}

// Round 6
// 329.268 us; speedup vs baseline: 2.3627x; 1.0630x over previous
//
#include <hip/hip_runtime.h>
#include <hip/hip_bf16.h>

#define N_NODES 50000
#define N_EDGES 1600000
#define HEADS 8
#define NBK 196   // buckets: dst>>8
#define NBLK 196  // edge tiles: 196*8192 >= 1.6M
#define EPB 8192  // edges per bucket-build block

typedef unsigned short u16;
typedef unsigned char u8;
typedef unsigned int u32;
typedef __attribute__((ext_vector_type(8))) short bf16x8;
typedef __attribute__((ext_vector_type(4))) float f32x4;

__device__ __forceinline__ float bf2f(u16 u) {
  union { u32 i; float f; } v; v.i = ((u32)u) << 16; return v.f;
}
__device__ __forceinline__ float bflo(u32 p) {
  union { u32 i; float f; } v; v.i = p << 16; return v.f;
}
__device__ __forceinline__ float bfhi(u32 p) {
  union { u32 i; float f; } v; v.i = p & 0xffff0000u; return v.f;
}
__device__ __forceinline__ u16 f2bf(float f) {
  union { float f; u32 i; } v; v.f = f;
  u32 r = v.i + 0x7fff + ((v.i >> 16) & 1);  // RNE
  return (u16)(r >> 16);
}
__device__ __forceinline__ u32 pack2(float a, float b) {
  return (u32)f2bf(a) | ((u32)f2bf(b) << 16);
}

// ---------------- dtype auto-detection ----------------
__global__ void k_detect(const u16* __restrict__ x, const u32* __restrict__ ei,
                         int* __restrict__ flags) {
  __shared__ int cbig, cnz;
  if (threadIdx.x == 0) { cbig = 0; cnz = 0; }
  __syncthreads();
  int lb = 0, ln = 0;
  for (int i = threadIdx.x; i < 4096; i += 256) {
    int ex = (x[i] >> 7) & 0xff;
    lb += (ex >= 140);
    if (i < 2048) ln += (ei[2 * i + 1] != 0);
  }
  atomicAdd(&cbig, lb); atomicAdd(&cnz, ln);
  __syncthreads();
  if (threadIdx.x == 0) {
    flags[0] = (cbig > 16) ? 1 : 0;   // 1: floats are fp32
    flags[1] = (cnz == 0) ? 1 : 0;    // 1: edge_index is int64
  }
}

// ---------------- converter: vectors -> fp32, W1/W2 -> transposed bf16 -------
__global__ void k_convsmall(const void* a1s, const void* a1d, const void* b1,
                            const void* gam, const void* bet, const void* a2s,
                            const void* a2d, const void* b2, const void* W1,
                            const void* W2, float* __restrict__ smallf,
                            u16* __restrict__ w1t, u16* __restrict__ w2t,
                            const int* __restrict__ flags) {
  int i = blockIdx.x * 256 + threadIdx.x;
  if (i >= 25408) return;
  bool f32 = flags[0] != 0;
  auto ld = [&](const void* p, int off) -> float {
    return f32 ? ((const float*)p)[off] : bf2f(((const u16*)p)[off]);
  };
  if (i >= 17216) {            // W2T[n][k], n<64, k<128  <- W2[k*64+n]
    int j = i - 17216, n = j >> 7, k = j & 127;
    w2t[j] = f2bf(ld(W2, k * 64 + n));
  } else if (i >= 832) {       // W1T[n][k], n<128, k<128 <- W1[k*128+n]
    int j = i - 832, n = j >> 7, k = j & 127;
    w1t[j] = f2bf(ld(W1, k * 128 + n));
  } else {
    const void* src; int off;
    if (i >= 768)      { src = b2;  off = i - 768; }
    else if (i >= 704) { src = a2d; off = i - 704; }
    else if (i >= 640) { src = a2s; off = i - 640; }
    else if (i >= 512) { src = bet; off = i - 512; }
    else if (i >= 384) { src = gam; off = i - 384; }
    else if (i >= 256) { src = b1;  off = i - 256; }
    else if (i >= 128) { src = a1d; off = i - 128; }
    else               { src = a1s; off = i; }
    smallf[i] = ld(src, off);
  }
}

// ---------------- CSR build (atomic-free two-level counting sort) ----------
__global__ __launch_bounds__(256) void k_hist(const int* __restrict__ ei,
                                              int* __restrict__ H,
                                              int* __restrict__ totals,
                                              const int* __restrict__ flags) {
  __shared__ int hist[NBK];
  int t = threadIdx.x, blk = blockIdx.x;
  for (int i = t; i < NBK; i += 256) hist[i] = 0;
  __syncthreads();
  bool i64 = flags[1] != 0;
  int base = blk * EPB;
  for (int k = 0; k < 32; k++) {
    int e = base + k * 256 + t;
    if (e < N_EDGES) {
      int d = i64 ? ei[2 * (N_EDGES + e)] : ei[N_EDGES + e];
      atomicAdd(&hist[d >> 8], 1);
    }
  }
  __syncthreads();
  for (int i = t; i < NBK; i += 256) {
    H[i * NBLK + blk] = hist[i];
    atomicAdd(&totals[i], hist[i]);
  }
}

__global__ void k_scan_tot(const int* __restrict__ totals, int* __restrict__ bucketBase) {
  __shared__ int tmp[256];
  int t = threadIdx.x;
  int v = (t < NBK) ? totals[t] : 0;
  tmp[t] = v; __syncthreads();
  for (int o = 1; o < 256; o <<= 1) {
    int x = (t >= o) ? tmp[t - o] : 0; __syncthreads();
    tmp[t] += x; __syncthreads();
  }
  if (t < NBK) bucketBase[t] = tmp[t] - v;
  if (t == NBK - 1) bucketBase[NBK] = tmp[t];
}

__global__ void k_scan_blk(const int* __restrict__ H, const int* __restrict__ bucketBase,
                           int* __restrict__ P) {
  __shared__ int tmp[256];
  int t = threadIdx.x, b = blockIdx.x;
  int v = (t < NBLK) ? H[b * NBLK + t] : 0;
  tmp[t] = v; __syncthreads();
  for (int o = 1; o < 256; o <<= 1) {
    int x = (t >= o) ? tmp[t - o] : 0; __syncthreads();
    tmp[t] += x; __syncthreads();
  }
  if (t < NBLK) P[b * NBLK + t] = bucketBase[b] + tmp[t] - v;
}

// k_bucket v2: LDS counting sort per 8192-edge tile, coalesced global writes.
__global__ __launch_bounds__(256) void k_bucket(const int* __restrict__ ei,
                                                const int* __restrict__ P,
                                                u32* __restrict__ buf,
                                                const int* __restrict__ flags) {
  __shared__ u32 sv[EPB];       // 32 KB sorted values
  __shared__ u16 rank[EPB];     // 16 KB rank within bucket
  __shared__ u8  sk8[EPB];      //  8 KB sorted keys
  __shared__ int cnt[NBK], scn[NBK], tmp[256];
  int t = threadIdx.x, blk = blockIdx.x;
  int base = blk * EPB;
  int nE = N_EDGES - base; if (nE > EPB) nE = EPB;
  for (int i = t; i < NBK; i += 256) cnt[i] = 0;
  __syncthreads();
  bool i64 = flags[1] != 0;
  // pass 1: rank capture
  for (int k = 0; k < EPB / 256; k++) {
    int li = k * 256 + t, e = base + li;
    if (li < nE) {
      int d = i64 ? ei[2 * (N_EDGES + e)] : ei[N_EDGES + e];
      rank[li] = (u16)atomicAdd(&cnt[d >> 8], 1);
    }
  }
  __syncthreads();
  // scan cnt -> scn (exclusive)
  int v = (t < NBK) ? cnt[t] : 0;
  tmp[t] = v; __syncthreads();
  for (int o = 1; o < 256; o <<= 1) {
    int x = (t >= o) ? tmp[t - o] : 0; __syncthreads();
    tmp[t] += x; __syncthreads();
  }
  if (t < NBK) scn[t] = tmp[t] - v;
  __syncthreads();
  // pass 2: place into LDS sorted order
  for (int k = 0; k < EPB / 256; k++) {
    int li = k * 256 + t, e = base + li;
    if (li < nE) {
      int s = i64 ? ei[2 * e] : ei[e];
      int d = i64 ? ei[2 * (N_EDGES + e)] : ei[N_EDGES + e];
      int key = d >> 8;
      int pos = scn[key] + rank[li];
      sv[pos] = ((u32)(d & 255) << 16) | (u32)s;
      sk8[pos] = (u8)key;
    }
  }
  __syncthreads();
  // pass 3: coalesced run writes
  for (int i = t; i < nE; i += 256) {
    int b = sk8[i];
    buf[P[b * NBLK + blk] + (i - scn[b])] = sv[i];
  }
}

__global__ __launch_bounds__(256) void k_csr(const u32* __restrict__ buf,
                                             const int* __restrict__ bucketBase,
                                             int* __restrict__ row_start,
                                             int* __restrict__ deg,
                                             int* __restrict__ csr, int N) {
  __shared__ int cnt[256], scn[256], cur[256];
  int b = blockIdx.x, t = threadIdx.x;
  int lo = bucketBase[b], hi = bucketBase[b + 1];
  cnt[t] = 0; __syncthreads();
  for (int e = lo + t; e < hi; e += 256) atomicAdd(&cnt[(buf[e] >> 16) & 255], 1);
  __syncthreads();
  int v = cnt[t];
  scn[t] = v; __syncthreads();
  for (int o = 1; o < 256; o <<= 1) {
    int x = (t >= o) ? scn[t - o] : 0; __syncthreads();
    scn[t] += x; __syncthreads();
  }
  int excl = scn[t] - v;
  int node = b * 256 + t;
  if (node < N) { row_start[node] = lo + excl; deg[node] = v; }
  cur[t] = lo + excl;
  __syncthreads();
  for (int e = lo + t; e < hi; e += 256) {
    u32 p = buf[e];
    int pos = atomicAdd(&cur[(p >> 16) & 255], 1);
    csr[pos] = p & 0xffff;
  }
}

// ---------------- MFMA GEMM: A[M,128] x BT[NCOLS,128] -> bf16 C[M,NCOLS] ----
// EPI also fuses BN+ELU on A-load and alpha2 (a2 dot products) on the epilogue.
template <int NCOLS, bool EPI, bool AFLAG>
__global__ __launch_bounds__(256) void k_gemm_mfma(const void* __restrict__ A,
                                                   const u16* __restrict__ BT,
                                                   const float* __restrict__ scale,
                                                   const float* __restrict__ shift,
                                                   const float* __restrict__ a2s,
                                                   const float* __restrict__ a2d,
                                                   float* __restrict__ as_out,
                                                   float* __restrict__ ad_out,
                                                   u16* __restrict__ C, int M,
                                                   const int* __restrict__ flags) {
  constexpr int KP = 136;
  constexpr int NT = NCOLS / 16;
  __shared__ u16 As[64 * KP];
  __shared__ u16 Bs[NCOLS * KP];
  int t = threadIdx.x;
  int row0 = blockIdx.x * 64;
  bool af32 = AFLAG ? (flags[0] != 0) : false;

  for (int i = t; i < NCOLS * 16; i += 256) {
    int n = i >> 4, q = i & 15;
    *(uint4*)&Bs[n * KP + q * 8] = ((const uint4*)BT)[n * 16 + q];
  }
  for (int i = t; i < 64 * 32; i += 256) {
    int r = i >> 5, c4 = i & 31;
    int row = row0 + r;
    uint2 pk = make_uint2(0u, 0u);
    if (row < M) {
      if (EPI) {
        uint2 p = ((const uint2*)A)[(size_t)row * 32 + c4];
        int c = c4 * 4;
        float v0 = bflo(p.x), v1 = bfhi(p.x), v2 = bflo(p.y), v3 = bfhi(p.y);
        v0 = fmaf(v0, scale[c],     shift[c]);     v0 = v0 > 0.f ? v0 : __expf(v0) - 1.f;
        v1 = fmaf(v1, scale[c + 1], shift[c + 1]); v1 = v1 > 0.f ? v1 : __expf(v1) - 1.f;
        v2 = fmaf(v2, scale[c + 2], shift[c + 2]); v2 = v2 > 0.f ? v2 : __expf(v2) - 1.f;
        v3 = fmaf(v3, scale[c + 3], shift[c + 3]); v3 = v3 > 0.f ? v3 : __expf(v3) - 1.f;
        pk.x = pack2(v0, v1); pk.y = pack2(v2, v3);
      } else if (af32) {
        float4 v = ((const float4*)A)[(size_t)row * 32 + c4];
        pk.x = pack2(v.x, v.y); pk.y = pack2(v.z, v.w);
      } else {
        pk = ((const uint2*)A)[(size_t)row * 32 + c4];
      }
    }
    *(uint2*)&As[r * KP + c4 * 4] = pk;
  }
  __syncthreads();

  int lane = t & 63, w = t >> 6;
  int m = lane & 15, quad = lane >> 4;
  f32x4 acc[NT];
#pragma unroll
  for (int nt = 0; nt < NT; nt++) acc[nt] = (f32x4)(0.f);
  const u16* aBase = &As[(w * 16 + m) * KP + quad * 8];
  const u16* bBase = &Bs[m * KP + quad * 8];
#pragma unroll
  for (int ks = 0; ks < 4; ks++) {
    bf16x8 af = *(const bf16x8*)(aBase + ks * 32);
#pragma unroll
    for (int nt = 0; nt < NT; nt++) {
      bf16x8 bf = *(const bf16x8*)(bBase + nt * 16 * KP + ks * 32);
      acc[nt] = __builtin_amdgcn_mfma_f32_16x16x32_bf16(af, bf, acc[nt], 0, 0, 0);
    }
  }
  int orow0 = row0 + w * 16 + quad * 4;
#pragma unroll
  for (int nt = 0; nt < NT; nt++) {
#pragma unroll
    for (int r = 0; r < 4; r++) {
      int row = orow0 + r;
      if (row < M) C[(size_t)row * NCOLS + nt * 16 + m] = f2bf(acc[nt][r]);
    }
  }
  if (EPI) {  // fused alpha2: vs/vd per row, 16-lane reduction per quad group
    float a2sv[NT], a2dv[NT];
#pragma unroll
    for (int nt = 0; nt < NT; nt++) { a2sv[nt] = a2s[nt * 16 + m]; a2dv[nt] = a2d[nt * 16 + m]; }
#pragma unroll
    for (int r = 0; r < 4; r++) {
      float vs = 0.f, vd = 0.f;
#pragma unroll
      for (int nt = 0; nt < NT; nt++) {
        vs = fmaf(acc[nt][r], a2sv[nt], vs);
        vd = fmaf(acc[nt][r], a2dv[nt], vd);
      }
      vs += __shfl_xor(vs, 1); vd += __shfl_xor(vd, 1);
      vs += __shfl_xor(vs, 2); vd += __shfl_xor(vd, 2);
      vs += __shfl_xor(vs, 4); vd += __shfl_xor(vd, 4);
      vs += __shfl_xor(vs, 8); vd += __shfl_xor(vd, 8);
      int row = orow0 + r;
      if (row < M && m == 0) { as_out[row] = vs; ad_out[row] = vd; }
    }
  }
}

// ---------------- per-node attention coefficients, layer 1 ----------------
__global__ void k_alpha1(const u16* __restrict__ h1b, const float* __restrict__ a1s,
                         const float* __restrict__ a1d, float* __restrict__ as_out,
                         float* __restrict__ ad_out, int N) {
  int idx = blockIdx.x * 256 + threadIdx.x;
  if (idx >= N * HEADS) return;
  int n = idx >> 3, h = idx & 7;
  const u32* hp = (const u32*)&h1b[((size_t)n << 7) + (h << 4)];
  float s = 0.f, d = 0.f;
#pragma unroll
  for (int q = 0; q < 8; q++) {
    u32 p = hp[q];
    float v0 = bflo(p), v1 = bfhi(p);
    int b = (h << 4) + q * 2;
    s = fmaf(v0, a1s[b], s); s = fmaf(v1, a1s[b + 1], s);
    d = fmaf(v0, a1d[b], d); d = fmaf(v1, a1d[b + 1], d);
  }
  as_out[idx] = s; ad_out[idx] = d;
}

// ---------------- aggregation layer 1: shared-exp unroll 8 ----------------
// lane (head=l>>3, sub=l&7) computes exp for (edge=sub, head); p distributed
// to the other 7 lanes of the head group via shfl; s via group reduction.
__global__ __launch_bounds__(256) void k_agg1(const u16* __restrict__ h1b,
                                              const float* __restrict__ as_,
                                              const float* __restrict__ ad_,
                                              const int* __restrict__ csr,
                                              const int* __restrict__ row_start,
                                              const int* __restrict__ deg,
                                              const float* __restrict__ b1,
                                              u16* __restrict__ out, int N) {
  int node = blockIdx.x * 4 + (threadIdx.x >> 6);
  if (node >= N) return;
  int l = threadIdx.x & 63;
  int head = l >> 3, sub = l & 7;
  int gbase = l & 56;  // base lane of this head group
  int node_u = __builtin_amdgcn_readfirstlane(node);
  int st = __builtin_amdgcn_readfirstlane(row_start[node_u]);
  int cnt = __builtin_amdgcn_readfirstlane(deg[node_u]);
  const int* cp = csr + st;
  const u32* h32 = (const u32*)h1b;
  float ad = ad_[(node_u << 3) | head];
  float sp = 0.f, a0 = 0.f, a1 = 0.f;
  int j = 0;
  for (; j + 8 <= cnt; j += 8) {
    int ssub = cp[j + sub];                       // per-lane: my slot's src
    float e = as_[(ssub << 3) | head] + ad;
    e = fmaxf(e, 0.2f * e);
    float p = __expf(e);
    sp += p;                                      // per-lane partial of s
#pragma unroll
    for (int k = 0; k < 8; k++) {
      int sk = cp[j + k];                         // uniform -> s_load
      float pk = __shfl(p, gbase | k);
      u32 hv = h32[(sk << 6) | l];
      a0 = fmaf(pk, bflo(hv), a0);
      a1 = fmaf(pk, bfhi(hv), a1);
    }
  }
  for (; j < cnt; j++) {
    int s0 = cp[j];
    float e0 = as_[(s0 << 3) | head] + ad;
    e0 = fmaxf(e0, 0.2f * e0);
    float p0 = __expf(e0);
    if (sub == 0) sp += p0;
    u32 hv = h32[(s0 << 6) | l];
    a0 = fmaf(p0, bflo(hv), a0); a1 = fmaf(p0, bfhi(hv), a1);
  }
  { // self-loop
    float e0 = as_[(node_u << 3) | head] + ad;
    e0 = fmaxf(e0, 0.2f * e0);
    float p0 = __expf(e0);
    if (sub == 0) sp += p0;
    u32 hv = h32[((size_t)node_u << 6) | l];
    a0 = fmaf(p0, bflo(hv), a0); a1 = fmaf(p0, bfhi(hv), a1);
  }
  sp += __shfl_xor(sp, 1);
  sp += __shfl_xor(sp, 2);
  sp += __shfl_xor(sp, 4);
  float inv = 1.f / (sp + 1e-16f);
  int c0 = l * 2;
  ((u32*)out)[((size_t)node_u << 6) + l] =
      pack2(fmaf(a0, inv, b1[c0]), fmaf(a1, inv, b1[c0 + 1]));
}

// ---------------- batch norm ----------------
__global__ void k_bnstat(const u16* __restrict__ h, float* __restrict__ gsum,
                         float* __restrict__ gsq, int N) {
  __shared__ float ts[256], tq[256];
  int t = threadIdx.x, col = t & 127, rr = t >> 7;
  int row0 = blockIdx.x * 128;
  float s = 0.f, q = 0.f;
  for (int r = rr; r < 128; r += 2) {
    int row = row0 + r;
    if (row < N) {
      float v = bf2f(h[((size_t)row << 7) + col]);
      s += v; q = fmaf(v, v, q);
    }
  }
  ts[t] = s; tq[t] = q; __syncthreads();
  if (t < 128) {
    atomicAdd(&gsum[t], ts[t] + ts[t + 128]);
    atomicAdd(&gsq[t], tq[t] + tq[t + 128]);
  }
}

__global__ void k_bnfin(const float* __restrict__ gsum, const float* __restrict__ gsq,
                        const float* __restrict__ gamma, const float* __restrict__ beta,
                        float* __restrict__ scale, float* __restrict__ shift, int N) {
  int t = threadIdx.x;
  if (t >= 128) return;
  float mu = gsum[t] / (float)N;
  float var = fmaxf(gsq[t] / (float)N - mu * mu, 0.f);
  float s = gamma[t] * rsqrtf(var + 1e-5f);
  scale[t] = s;
  shift[t] = beta[t] - mu * s;
}

// ---------------- aggregation layer 2 -> output (shared-exp unroll 8) -------
__global__ __launch_bounds__(256) void k_agg2(const u16* __restrict__ h2b,
                                              const float* __restrict__ as_,
                                              const float* __restrict__ ad_,
                                              const int* __restrict__ csr,
                                              const int* __restrict__ row_start,
                                              const int* __restrict__ deg,
                                              const float* __restrict__ b2,
                                              void* __restrict__ out,
                                              const int* __restrict__ flags, int N) {
  int node = blockIdx.x * 4 + (threadIdx.x >> 6);
  if (node >= N) return;
  int l = threadIdx.x & 63;
  int sub = l & 7, gbase = l & 56;
  int node_u = __builtin_amdgcn_readfirstlane(node);
  int st = __builtin_amdgcn_readfirstlane(row_start[node_u]);
  int cnt = __builtin_amdgcn_readfirstlane(deg[node_u]);
  const int* cp = csr + st;
  float ad = ad_[node_u];
  float sp = 0.f, a = 0.f;
  int j = 0;
  for (; j + 8 <= cnt; j += 8) {
    int ssub = cp[j + sub];
    float e = as_[ssub] + ad;
    e = fmaxf(e, 0.2f * e);
    float p = __expf(e);
    sp += p;
#pragma unroll
    for (int k = 0; k < 8; k++) {
      int sk = cp[j + k];                         // uniform -> s_load
      float pk = __shfl(p, gbase | k);
      a = fmaf(pk, bf2f((h2b + (sk << 6))[l]), a);
    }
  }
  for (; j < cnt; j++) {
    int s0 = cp[j];
    float e0 = as_[s0] + ad;
    e0 = fmaxf(e0, 0.2f * e0);
    float p0 = __expf(e0);
    if (sub == 0) sp += p0;
    a = fmaf(p0, bf2f((h2b + (s0 << 6))[l]), a);
  }
  { // self-loop
    float e0 = as_[node_u] + ad;
    e0 = fmaxf(e0, 0.2f * e0);
    float p0 = __expf(e0);
    if (sub == 0) sp += p0;
    a = fmaf(p0, bf2f((h2b + (node_u << 6))[l]), a);
  }
  sp += __shfl_xor(sp, 1);
  sp += __shfl_xor(sp, 2);
  sp += __shfl_xor(sp, 4);
  float r = a / (sp + 1e-16f) + b2[l];
  size_t idx = ((size_t)node_u << 6) + l;
  if (flags[0]) ((float*)out)[idx] = r;
  else          ((u16*)out)[idx] = f2bf(r);
}

extern "C" void kernel_launch(void* const* d_in, const int* in_sizes, int n_in,
                              void* d_out, int out_size, void* d_ws, size_t ws_size,
                              hipStream_t stream) {
  const void* x   = d_in[0];
  const int*  ei  = (const int*)d_in[1];
  const void* W1  = d_in[2];
  const void* a1s = d_in[3];
  const void* a1d = d_in[4];
  const void* b1  = d_in[5];
  const void* gam = d_in[6];
  const void* bet = d_in[7];
  const void* W2  = d_in[8];
  const void* a2s = d_in[9];
  const void* a2d = d_in[10];
  const void* b2  = d_in[11];

  char* ws = (char*)d_ws;
  size_t off = 0;
  auto alloc = [&](size_t bytes) -> void* {
    void* p = ws + off;
    off += (bytes + 255) & ~(size_t)255;
    return p;
  };
  int* flags = (int*)alloc(256);
  char* zreg = (char*)alloc(2048);  // totals[196] | gsum[128] | gsq[128]
  int* totals = (int*)zreg;
  float* gsum = (float*)(zreg + 1024);
  float* gsq  = gsum + 128;
  int* H  = (int*)alloc((size_t)NBK * NBLK * 4);
  int* P  = (int*)alloc((size_t)NBK * NBLK * 4);
  int* bucketBase = (int*)alloc(1024);
  u32* ebuf = (u32*)alloc((size_t)N_EDGES * 4);
  int* csr = (int*)alloc((size_t)N_EDGES * 4);
  int* row_start = (int*)alloc((size_t)N_NODES * 4);
  int* deg = (int*)alloc((size_t)N_NODES * 4);
  float* smallf = (float*)alloc(832 * 4);
  float* a1sf = smallf;        float* a1df = smallf + 128;
  float* b1f  = smallf + 256;  float* gamf = smallf + 384;
  float* betf = smallf + 512;  float* a2sf = smallf + 640;
  float* a2df = smallf + 704;  float* b2f  = smallf + 768;
  u16* w1t = (u16*)alloc(16384 * 2);
  u16* w2t = (u16*)alloc(8192 * 2);
  u16* h1b  = (u16*)alloc((size_t)N_NODES * 128 * 2);
  u16* h1ob = (u16*)alloc((size_t)N_NODES * 128 * 2);
  u16* h2b  = (u16*)alloc((size_t)N_NODES * 64 * 2);
  float* al1s = (float*)alloc((size_t)N_NODES * 8 * 4);
  float* al1d = (float*)alloc((size_t)N_NODES * 8 * 4);
  float* scale = (float*)alloc(512);
  float* shift = (float*)alloc(512);
  float* al2s = (float*)alloc((size_t)N_NODES * 4);
  float* al2d = (float*)alloc((size_t)N_NODES * 4);
  if (off > ws_size) return;

  hipMemsetAsync(zreg, 0, 2048, stream);
  k_detect<<<1, 256, 0, stream>>>((const u16*)x, (const u32*)ei, flags);
  k_convsmall<<<100, 256, 0, stream>>>(a1s, a1d, b1, gam, bet, a2s, a2d, b2, W1, W2,
                                       smallf, w1t, w2t, flags);

  // ---- CSR build ----
  k_hist<<<NBLK, 256, 0, stream>>>(ei, H, totals, flags);
  k_scan_tot<<<1, 256, 0, stream>>>(totals, bucketBase);
  k_scan_blk<<<NBK, 256, 0, stream>>>(H, bucketBase, P);
  k_bucket<<<NBLK, 256, 0, stream>>>(ei, P, ebuf, flags);
  k_csr<<<NBK, 256, 0, stream>>>(ebuf, bucketBase, row_start, deg, csr, N_NODES);

  // ---- layer 1 ----
  k_gemm_mfma<128, false, true><<<(N_NODES + 63) / 64, 256, 0, stream>>>(
      x, w1t, nullptr, nullptr, nullptr, nullptr, nullptr, nullptr, h1b, N_NODES, flags);
  k_alpha1<<<(N_NODES * HEADS + 255) / 256, 256, 0, stream>>>(h1b, a1sf, a1df,
                                                              al1s, al1d, N_NODES);
  k_agg1<<<(N_NODES + 3) / 4, 256, 0, stream>>>(h1b, al1s, al1d, csr, row_start, deg,
                                                b1f, h1ob, N_NODES);

  // ---- BN ----
  k_bnstat<<<(N_NODES + 127) / 128, 256, 0, stream>>>(h1ob, gsum, gsq, N_NODES);
  k_bnfin<<<1, 128, 0, stream>>>(gsum, gsq, gamf, betf, scale, shift, N_NODES);

  // ---- layer 2 (alpha2 fused into GEMM epilogue) ----
  k_gemm_mfma<64, true, false><<<(N_NODES + 63) / 64, 256, 0, stream>>>(
      h1ob, w2t, scale, shift, a2sf, a2df, al2s, al2d, h2b, N_NODES, flags);
  k_agg2<<<(N_NODES + 3) / 4, 256, 0, stream>>>(h2b, al2s, al2d, csr, row_start, deg,
                                                b2f, d_out, flags, N_NODES);
}